// Round 8
// baseline (677.988 us; speedup 1.0000x reference)
//
#include <hip/hip_runtime.h>
#include <math.h>

#define Bv  64
#define Tv  512
#define Dv  256
#define FFv 512
#define Lv  4
#define BTv (Bv*Tv)
#define EPSv 1e-5f
// Q scale: 1/sqrt(32) * log2(e)  (log2e folded so attn uses raw v_exp_f32 = 2^x)
#define QSC 0.25509402f

typedef __attribute__((ext_vector_type(8))) short short8;
typedef __attribute__((ext_vector_type(4))) float f32x4;
typedef unsigned short us;

#if __has_builtin(__builtin_amdgcn_exp2f)
#define EXP2(x) __builtin_amdgcn_exp2f(x)
#else
#define EXP2(x) exp2f(x)
#endif

// counted vmcnt wait (T4): retire oldest stage, keep newer stages in flight
#define WAITV(n) asm volatile("s_waitcnt vmcnt(" #n ")" ::: "memory")

// single f32 -> bf16 (RNE) via v_cvt_pk_bf16_f32, 1 VALU inst
__device__ __forceinline__ us f2bf(float f) {
    unsigned r;
    asm("v_cvt_pk_bf16_f32 %0, %1, 0" : "=v"(r) : "v"(f));
    return (us)r;
}
// pack two f32 -> 2x bf16 (lo=a, hi=b), 1 VALU inst
__device__ __forceinline__ unsigned pk2(float a, float b) {
    unsigned r;
    asm("v_cvt_pk_bf16_f32 %0, %1, %2" : "=v"(r) : "v"(a), "v"(b));
    return r;
}
__device__ __forceinline__ float wave_sum(float v) {
#pragma unroll
    for (int o = 32; o > 0; o >>= 1) v += __shfl_xor(v, o);
    return v;
}

// ---------------- all weight converts in one launch -------------------------
__global__ __launch_bounds__(256) void cvtall_kernel(
    const float* __restrict__ qw, const float* __restrict__ ow,
    const float* __restrict__ f1, const float* __restrict__ f2,
    const float* __restrict__ qb,
    us* __restrict__ wq, us* __restrict__ wo, us* __restrict__ w1,
    us* __restrict__ w2, float* __restrict__ sb)
{
    int blk = blockIdx.x, tid = threadIdx.x;
    if (blk < 2048) {
        const float* s; us* d; int i; float sc = 1.0f;
        if (blk < 768)       { i = blk*256 + tid;        s = qw; d = wq;
                               sc = (((i >> 6) % 768) < 256) ? QSC : 1.0f; }
        else if (blk < 1024) { i = (blk-768)*256 + tid;  s = ow; d = wo; }
        else if (blk < 1536) { i = (blk-1024)*256 + tid; s = f1; d = w1; }
        else                 { i = (blk-1536)*256 + tid; s = f2; d = w2; }
        float4 v = ((const float4*)s)[i];
        uint2 o;
        o.x = pk2(v.x*sc, v.y*sc);
        o.y = pk2(v.z*sc, v.w*sc);
        ((uint2*)d)[i] = o;
    } else {
        int i = (blk-2048)*256 + tid;
        sb[i] = qb[i] * (((i % 768) < 256) ? QSC : 1.0f);
    }
}

// ---------------- embed + LN: 4 rows/block, one wave per row, float4 --------
__global__ __launch_bounds__(256) void embed_ln_kernel(
    const float* __restrict__ lat, const int* __restrict__ mids,
    const float* __restrict__ pos, const float* __restrict__ ef,
    const float* __restrict__ et,  const float* __restrict__ ep,
    const float* __restrict__ nw,  const float* __restrict__ nb,
    float* __restrict__ x, us* __restrict__ xn)
{
    int wv = threadIdx.x >> 6, lane = threadIdx.x & 63;
    size_t row = (size_t)blockIdx.x * 4 + wv;
    int t  = (int)(row & (Tv - 1));
    int id = mids[row];
    int promo = id >> 12;
    int rem   = id & 4095;
    int frm   = rem >> 6;
    int to    = rem & 63;
    float4 v  = ((const float4*)(lat + row*Dv))[lane];
    float4 pv = ((const float4*)(pos + (size_t)t*Dv))[lane];
    float4 fv = ((const float4*)(ef + (size_t)frm*Dv))[lane];
    float4 tv = ((const float4*)(et + (size_t)to*Dv))[lane];
    float4 ev = ((const float4*)(ep + (size_t)promo*Dv))[lane];
    v.x += pv.x + fv.x + tv.x + ev.x;
    v.y += pv.y + fv.y + tv.y + ev.y;
    v.z += pv.z + fv.z + tv.z + ev.z;
    v.w += pv.w + fv.w + tv.w + ev.w;
    ((float4*)(x + row*Dv))[lane] = v;
    float mu = wave_sum(v.x + v.y + v.z + v.w) * (1.0f/Dv);
    float dx = v.x-mu, dy = v.y-mu, dz = v.z-mu, dw = v.w-mu;
    float var = wave_sum(dx*dx + dy*dy + dz*dz + dw*dw) * (1.0f/Dv);
    float inv = rsqrtf(var + EPSv);
    float4 w4 = ((const float4*)nw)[lane];
    float4 b4 = ((const float4*)nb)[lane];
    uint2 o;
    o.x = pk2(dx*inv*w4.x + b4.x, dy*inv*w4.y + b4.y);
    o.y = pk2(dz*inv*w4.z + b4.z, dw*inv*w4.w + b4.w);
    ((uint2*)(xn + row*Dv))[lane] = o;
}

// ---------------- final: LN + mask select (fp32 out) ------------------------
__global__ __launch_bounds__(256) void final_kernel(
    const float* __restrict__ x, const float* __restrict__ lat,
    const int* __restrict__ mask, const float* __restrict__ w,
    const float* __restrict__ b, float* __restrict__ out)
{
    int wv = threadIdx.x >> 6, lane = threadIdx.x & 63;
    size_t row = (size_t)blockIdx.x * 4 + wv;
    float4 v = ((const float4*)(x + row*Dv))[lane];
    float mu = wave_sum(v.x + v.y + v.z + v.w) * (1.0f/Dv);
    float dx = v.x-mu, dy = v.y-mu, dz = v.z-mu, dw = v.w-mu;
    float var = wave_sum(dx*dx + dy*dy + dz*dz + dw*dw) * (1.0f/Dv);
    float inv = rsqrtf(var + EPSv);
    float4 w4 = ((const float4*)w)[lane];
    float4 b4 = ((const float4*)b)[lane];
    float4 o;
    o.x = dx*inv*w4.x + b4.x;
    o.y = dy*inv*w4.y + b4.y;
    o.z = dz*inv*w4.z + b4.z;
    o.w = dw*inv*w4.w + b4.w;
    if (!mask[row]) o = ((const float4*)(lat + row*Dv))[lane];
    ((float4*)(out + row*Dv))[lane] = o;
}

// ---------------- bf16 MFMA GEMM (128x128 tile, BK=64, XOR-swizzled LDS) ----
// T4 counted-vmcnt 2-deep pipeline (r7). NEW: coalesced C epilogue — acc is
// transposed through the (now free) As/Bs LDS with stride 132 (2-way banks =
// free), then stored as 8x16B coalesced per thread instead of 64x2B scatter.
template<int RELU>
__global__ __launch_bounds__(256) void mm_kernel(
    const us* __restrict__ A, const us* __restrict__ B,
    const float* __restrict__ bias, us* __restrict__ C,
    int M, int N, int K)
{
    __shared__ us As[2][128*64];
    __shared__ us Bs[2][128*64];
    int tid  = threadIdx.x;
    int lane = tid & 63;
    int wu   = __builtin_amdgcn_readfirstlane(tid >> 6);
    int m0 = blockIdx.x * 128, n0 = blockIdx.y * 128;
    int wm = wu & 1, wn = wu >> 1;
    f32x4 acc[4][4] = {};
    int srow = lane >> 3;
    int sg   = (lane & 7) ^ srow;
    const us* Ag = A + (size_t)m0 * K + sg*8;
    const us* Bg = B + (size_t)n0 * K + sg*8;
    int cc = lane & 15, q4 = lane >> 4;

#define STG(kk, bb) { \
    _Pragma("unroll") \
    for (int p = 0; p < 4; p++) { \
        int row = wu*32 + p*8; \
        __builtin_amdgcn_global_load_lds( \
            (const __attribute__((address_space(1))) unsigned int*)(Ag + (size_t)(row + srow)*K + (kk)), \
            (__attribute__((address_space(3))) unsigned int*)(&As[bb][row*64]), \
            16, 0, 0); \
        __builtin_amdgcn_global_load_lds( \
            (const __attribute__((address_space(1))) unsigned int*)(Bg + (size_t)(row + srow)*K + (kk)), \
            (__attribute__((address_space(3))) unsigned int*)(&Bs[bb][row*64]), \
            16, 0, 0); \
    } }

    int nk = K >> 6;
    STG(0, 0);
    if (nk > 1) STG(64, 1);
    int cur = 0;
    for (int t = 0; t < nk; t++) {
        if (t < nk - 1) { WAITV(8); } else { WAITV(0); }   // retire stage t only
        __builtin_amdgcn_s_barrier();
        __builtin_amdgcn_sched_barrier(0);
#pragma unroll
        for (int h = 0; h < 2; h++) {
            int pg = ((h*4 + q4) ^ (cc & 7)) * 8;
            short8 av[4], bv[4];
#pragma unroll
            for (int i = 0; i < 4; i++)
                av[i] = *(const short8*)(&As[cur][(wm*64 + i*16 + cc)*64 + pg]);
#pragma unroll
            for (int j = 0; j < 4; j++)
                bv[j] = *(const short8*)(&Bs[cur][(wn*64 + j*16 + cc)*64 + pg]);
#pragma unroll
            for (int i = 0; i < 4; i++)
#pragma unroll
                for (int j = 0; j < 4; j++)
                    acc[i][j] = __builtin_amdgcn_mfma_f32_16x16x32_bf16(av[i], bv[j], acc[i][j], 0, 0, 0);
        }
        __builtin_amdgcn_sched_barrier(0);
        __builtin_amdgcn_s_barrier();
        __builtin_amdgcn_sched_barrier(0);
        if (t + 2 < nk) STG((t+2)*64, cur);                 // refill freed buffer
        cur ^= 1;
    }
#undef STG

    // ---- coalesced epilogue: acc -> LDS (stride 132) -> 16B global stores --
    // rows 0..63 (wm=0) live in As, rows 64..127 (wm=1) in Bs. Loop's final
    // s_barrier guarantees all As/Bs reads are done.
    {
        us* Cs = wm ? &Bs[0][0] : &As[0][0];
#pragma unroll
        for (int j = 0; j < 4; j++) {
            int n = wn*64 + j*16 + cc;
            float bj = bias[n0 + n];
#pragma unroll
            for (int i = 0; i < 4; i++) {
#pragma unroll
                for (int r = 0; r < 4; r++) {
                    float v = acc[i][j][r] + bj;
                    if (RELU) v = fmaxf(v, 0.f);
                    Cs[(i*16 + q4*4 + r)*132 + n] = f2bf(v);
                }
            }
        }
        __syncthreads();
        int row = tid >> 1, half = tid & 1;                 // 128 rows x 2 halves
        const us* src = (row < 64 ? &As[0][0] + row*132
                                  : &Bs[0][0] + (row - 64)*132) + half*64;
        us* dst = C + (size_t)(m0 + row) * N + n0 + half*64;
#pragma unroll
        for (int k = 0; k < 8; k++)
            *(short8*)(dst + k*8) = *(const short8*)(src + k*8);
    }
}

// ---------------- fused GEMM 128x256 tile + residual + fused LN -------------
// T4 counted-vmcnt 2-deep pipeline (6 loads/stage/thread -> vmcnt(6)).
__global__ __launch_bounds__(512) void mmfuse_kernel(
    const us* __restrict__ A, const us* __restrict__ B,
    const float* __restrict__ bias, float* __restrict__ x,
    us* __restrict__ xn, const float* __restrict__ nw,
    const float* __restrict__ nb, int M, int K)
{
    __shared__ us As[2][128*64];
    __shared__ us Bs[2][256*64];
    __shared__ float red[128][4][2];
    __shared__ float mus[128], rss[128];
    int tid  = threadIdx.x;
    int lane = tid & 63;
    int wu   = __builtin_amdgcn_readfirstlane(tid >> 6);   // 0..7
    int m0 = blockIdx.x * 128;
    int wm = wu & 1, wn = wu >> 1;                          // 2m x 4n waves
    f32x4 acc[4][4] = {};
    int srow = lane >> 3;
    int sg   = (lane & 7) ^ srow;
    const us* Ag = A + (size_t)m0 * K + sg*8;
    const us* Bg = B + sg*8;
    int cc = lane & 15, q4 = lane >> 4;

#define STG(kk, bb) { \
    _Pragma("unroll") \
    for (int p = 0; p < 2; p++) { \
        int row = wu*16 + p*8; \
        __builtin_amdgcn_global_load_lds( \
            (const __attribute__((address_space(1))) unsigned int*)(Ag + (size_t)(row + srow)*K + (kk)), \
            (__attribute__((address_space(3))) unsigned int*)(&As[bb][row*64]), \
            16, 0, 0); \
    } \
    _Pragma("unroll") \
    for (int p = 0; p < 4; p++) { \
        int row = wu*32 + p*8; \
        __builtin_amdgcn_global_load_lds( \
            (const __attribute__((address_space(1))) unsigned int*)(Bg + (size_t)(row + srow)*K + (kk)), \
            (__attribute__((address_space(3))) unsigned int*)(&Bs[bb][row*64]), \
            16, 0, 0); \
    } }

    int nk = K >> 6;
    STG(0, 0);
    if (nk > 1) STG(64, 1);
    int cur = 0;
    for (int t = 0; t < nk; t++) {
        if (t < nk - 1) { WAITV(6); } else { WAITV(0); }
        __builtin_amdgcn_s_barrier();
        __builtin_amdgcn_sched_barrier(0);
#pragma unroll
        for (int h = 0; h < 2; h++) {
            int pg = ((h*4 + q4) ^ (cc & 7)) * 8;
            short8 av[4], bv[4];
#pragma unroll
            for (int i = 0; i < 4; i++)
                av[i] = *(const short8*)(&As[cur][(wm*64 + i*16 + cc)*64 + pg]);
#pragma unroll
            for (int j = 0; j < 4; j++)
                bv[j] = *(const short8*)(&Bs[cur][(wn*64 + j*16 + cc)*64 + pg]);
#pragma unroll
            for (int i = 0; i < 4; i++)
#pragma unroll
                for (int j = 0; j < 4; j++)
                    acc[i][j] = __builtin_amdgcn_mfma_f32_16x16x32_bf16(av[i], bv[j], acc[i][j], 0, 0, 0);
        }
        __builtin_amdgcn_sched_barrier(0);
        __builtin_amdgcn_s_barrier();
        __builtin_amdgcn_sched_barrier(0);
        if (t + 2 < nk) STG((t+2)*64, cur);
        cur ^= 1;
    }
#undef STG

    // ---- epilogue: bias + residual + x write + fused LN -> xn -------------
    float bb4[4], nwv[4], nbv[4];
#pragma unroll
    for (int j = 0; j < 4; j++) {
        int n = wn*64 + j*16 + cc;
        bb4[j] = bias[n]; nwv[j] = nw[n]; nbv[j] = nb[n];
    }
#pragma unroll
    for (int i = 0; i < 4; i++) {
        float s[4] = {0.f,0.f,0.f,0.f}, sq[4] = {0.f,0.f,0.f,0.f};
#pragma unroll
        for (int j = 0; j < 4; j++) {
#pragma unroll
            for (int r = 0; r < 4; r++) {
                int ml = wm*64 + i*16 + q4*4 + r;
                size_t off = (size_t)(m0 + ml) * Dv + wn*64 + j*16 + cc;
                float v = acc[i][j][r] + bb4[j] + x[off];
                acc[i][j][r] = v;
                x[off] = v;
                s[r] += v; sq[r] += v*v;
            }
        }
#pragma unroll
        for (int r = 0; r < 4; r++) {
#pragma unroll
            for (int o = 1; o < 16; o <<= 1) {
                s[r]  += __shfl_xor(s[r],  o);
                sq[r] += __shfl_xor(sq[r], o);
            }
        }
        if (cc == 0) {
#pragma unroll
            for (int r = 0; r < 4; r++) {
                red[wm*64 + i*16 + q4*4 + r][wn][0] = s[r];
                red[wm*64 + i*16 + q4*4 + r][wn][1] = sq[r];
            }
        }
    }
    __syncthreads();
    if (tid < 128) {
        float ts = red[tid][0][0] + red[tid][1][0] + red[tid][2][0] + red[tid][3][0];
        float tq = red[tid][0][1] + red[tid][1][1] + red[tid][2][1] + red[tid][3][1];
        float mu = ts * (1.0f/Dv);
        float var = tq * (1.0f/Dv) - mu*mu;
        mus[tid] = mu;
        rss[tid] = rsqrtf(var + EPSv);
    }
    __syncthreads();
#pragma unroll
    for (int i = 0; i < 4; i++) {
#pragma unroll
        for (int r = 0; r < 4; r++) {
            int ml = wm*64 + i*16 + q4*4 + r;
            float mu = mus[ml], rv = rss[ml];
#pragma unroll
            for (int j = 0; j < 4; j++) {
                size_t off = (size_t)(m0 + ml) * Dv + wn*64 + j*16 + cc;
                xn[off] = f2bf((acc[i][j][r] - mu)*rv*nwv[j] + nbv[j]);
            }
        }
    }
}

// ---------------- MFMA flash attention (S^T form, 2-deep pipelined) ---------
// Q pre-scaled by 1/sqrt(32)*log2e -> softmax numerator = exp2(s).
// Diag-tile skip: wave wu only needs key sub-tiles jt <= wu (block-causal);
// jt > wu are fully masked -> skip QK MFMA + exp, zero-fill Ps; lane mask
// applied only at jt == wu; PV kk=1 skipped when its P rows are all zero.
__global__ __launch_bounds__(256) void attn_kernel(
    const us* __restrict__ qkv, us* __restrict__ ao)
{
    int blk = blockIdx.x;
    int b  = blk & 63;
    int h  = (blk >> 6) & 7;
    int qt = blk >> 9;
    int i0 = qt << 6;
    int tid = threadIdx.x;
    int lane = tid & 63;
    int wu = tid >> 6;

    __shared__ us Ks[2][64][40];
    __shared__ us Vt[2][32][72];
    __shared__ us Ps[4][16][72];
    __shared__ float Ls[4][16];

    size_t rowbase = (size_t)b * Tv;
    int c = lane & 15, q4 = lane >> 4;

    short8 qfrag = *(const short8*)(qkv + (rowbase + i0 + wu*16 + c)*768 + h*32 + q4*8);

    int skey = tid >> 2, sdc = (tid & 3) << 3;
    int vkey = tid & 63, vg = tid >> 6;
    const us* kgp = qkv + (rowbase + skey)*768 + 256 + h*32 + sdc;
    const us* vgp = qkv + (rowbase + vkey)*768 + 512 + h*32 + vg*8;

    f32x4 oacc[2] = {};
    float lsum = 0.f;
    int ntiles = qt + 1;

    short8 kreg = *(const short8*)(kgp);
    short8 vreg = *(const short8*)(vgp);
    *(short8*)&Ks[0][skey][sdc] = kreg;
#pragma unroll
    for (int j = 0; j < 8; j++) Vt[0][vg*8 + j][vkey] = vreg[j];
    if (ntiles > 1) {
        kreg = *(const short8*)(kgp + 64*768);
        vreg = *(const short8*)(vgp + 64*768);
    }
    __syncthreads();

    for (int kt = 0; kt < ntiles; kt++) {
        int cur = kt & 1;
        if (kt + 1 < ntiles) {
            *(short8*)&Ks[cur^1][skey][sdc] = kreg;
#pragma unroll
            for (int j = 0; j < 8; j++) Vt[cur^1][vg*8 + j][vkey] = vreg[j];
        }
        if (kt + 2 < ntiles) {
            kreg = *(const short8*)(kgp + (size_t)(kt+2)*64*768);
            vreg = *(const short8*)(vgp + (size_t)(kt+2)*64*768);
        }

        bool diag = (kt == ntiles - 1);
        int jtend = diag ? (wu + 1) : 4;      // wave-uniform
        f32x4 st[4];
#pragma unroll
        for (int jt = 0; jt < 4; jt++) {
            if (jt < jtend) {
                short8 kf = *(const short8*)&Ks[cur][jt*16 + c][q4*8];
                st[jt] = __builtin_amdgcn_mfma_f32_16x16x32_bf16(kf, qfrag, (f32x4){0.f,0.f,0.f,0.f}, 0, 0, 0);
            }
        }
#pragma unroll
        for (int jt = 0; jt < 4; jt++) {
            if (jt < jtend) {
                float msk = (diag && jt == wu) ? (((q4 >> 1) <= (c >> 3)) ? 1.f : 0.f) : 1.f;
                float p0 = EXP2(st[jt][0]) * msk;
                float p1 = EXP2(st[jt][1]) * msk;
                float p2 = EXP2(st[jt][2]) * msk;
                float p3 = EXP2(st[jt][3]) * msk;
                lsum += p0 + p1 + p2 + p3;
                uint2 w2; w2.x = pk2(p0, p1); w2.y = pk2(p2, p3);
                *(uint2*)&Ps[wu][c][jt*16 + q4*4] = w2;
            } else {
                uint2 z; z.x = 0u; z.y = 0u;
                *(uint2*)&Ps[wu][c][jt*16 + q4*4] = z;
            }
        }
        int kkend = (diag && wu < 2) ? 1 : 2; // P rows for kk=1 all zero
#pragma unroll
        for (int kk = 0; kk < 2; kk++) {
            if (kk < kkend) {
                short8 pf = *(const short8*)&Ps[wu][c][kk*32 + q4*8];
#pragma unroll
                for (int dt = 0; dt < 2; dt++) {
                    short8 vf = *(const short8*)&Vt[cur][dt*16 + c][kk*32 + q4*8];
                    oacc[dt] = __builtin_amdgcn_mfma_f32_16x16x32_bf16(pf, vf, oacc[dt], 0, 0, 0);
                }
            }
        }
        __syncthreads();
    }

    float l = lsum;
    l += __shfl_xor(l, 16);
    l += __shfl_xor(l, 32);
    if (q4 == 0) Ls[wu][c] = 1.0f / l;
    float4 lv4 = *(const float4*)&Ls[wu][q4*4];
#pragma unroll
    for (int dt = 0; dt < 2; dt++) {
#pragma unroll
        for (int r = 0; r < 4; r++) {
            float li = (r == 0) ? lv4.x : (r == 1) ? lv4.y : (r == 2) ? lv4.z : lv4.w;
            ao[(rowbase + i0 + wu*16 + q4*4 + r)*256 + h*32 + dt*16 + c] = f2bf(oacc[dt][r] * li);
        }
    }
}

// ---------------- launch ----------------------------------------------------
extern "C" void kernel_launch(void* const* d_in, const int* in_sizes, int n_in,
                              void* d_out, int out_size, void* d_ws, size_t ws_size,
                              hipStream_t stream)
{
    const float* latents    = (const float*)d_in[0];
    const int*   move_ids   = (const int*)  d_in[1];
    const int*   mask       = (const int*)  d_in[2];
    const float* positional = (const float*)d_in[3];
    const float* embed_from = (const float*)d_in[4];
    const float* embed_to   = (const float*)d_in[5];
    const float* embed_promo= (const float*)d_in[6];
    const float* in_proj_w  = (const float*)d_in[7];
    const float* in_proj_b  = (const float*)d_in[8];
    const float* out_w      = (const float*)d_in[9];
    const float* out_b      = (const float*)d_in[10];
    const float* fc1_w      = (const float*)d_in[11];
    const float* fc1_b      = (const float*)d_in[12];
    const float* fc2_w      = (const float*)d_in[13];
    const float* fc2_b      = (const float*)d_in[14];
    const float* norm_w     = (const float*)d_in[15];
    const float* norm_b     = (const float*)d_in[16];
    float* out = (float*)d_out;

    float* x   = (float*)d_ws;                              // BT*256 f32
    float* sb  = x + (size_t)BTv * Dv;                      // L*768 f32
    us* xn  = (us*)(sb + Lv*768);                           // BT*256 bf16
    us* qkv = xn + (size_t)BTv * Dv;                        // BT*768
    us* ao  = qkv + (size_t)BTv * 768;                      // BT*256
    us* h1  = ao + (size_t)BTv * Dv;                        // BT*512 bf16 (ffn intermediate)
    us* wq  = h1 + (size_t)BTv * FFv;                       // L*768*256
    us* wo  = wq + (size_t)Lv * 768 * Dv;
    us* w1  = wo + (size_t)Lv * Dv * Dv;
    us* w2  = w1 + (size_t)Lv * FFv * Dv;

    cvtall_kernel<<<2060, 256, 0, stream>>>(in_proj_w, out_w, fc1_w, fc2_w,
                                            in_proj_b, wq, wo, w1, w2, sb);

    embed_ln_kernel<<<BTv/4, 256, 0, stream>>>(latents, move_ids, positional,
        embed_from, embed_to, embed_promo, norm_w, norm_b, x, xn);

    for (int l = 0; l < Lv; l++) {
        // QKV: 128^2 tile, counted-vmcnt pipeline + coalesced epilogue
        mm_kernel<0><<<dim3(BTv/128, 768/128), 256, 0, stream>>>(
            xn, wq + (size_t)l*768*Dv, sb + l*768, qkv, BTv, 768, Dv);
        attn_kernel<<<Bv*8*(Tv/64), 256, 0, stream>>>(qkv, ao);
        // attn-out proj + residual + LN (K=256)
        mmfuse_kernel<<<BTv/128, 512, 0, stream>>>(
            ao, wo + (size_t)l*Dv*Dv, out_b + l*Dv, x, xn, norm_w, norm_b,
            BTv, Dv);
        // FFN phase 1: h1 = relu(xn @ W1^T + b1)
        mm_kernel<1><<<dim3(BTv/128, FFv/128), 256, 0, stream>>>(
            xn, w1 + (size_t)l*FFv*Dv, fc1_b + l*FFv, h1, BTv, FFv, Dv);
        // FFN phase 2: x += h1 @ W2^T + b2 ; xn = LN(x)  (K=512)
        mmfuse_kernel<<<BTv/128, 512, 0, stream>>>(
            h1, w2 + (size_t)l*Dv*FFv, fc2_b + l*Dv, x, xn, norm_w, norm_b,
            BTv, FFv);
    }
    final_kernel<<<BTv/4, 256, 0, stream>>>(x, latents, mask, norm_w, norm_b, out);
}

// Round 9
// 616.865 us; speedup vs baseline: 1.0991x; 1.0991x over previous
//
#include <hip/hip_runtime.h>
#include <math.h>

#define Bv  64
#define Tv  512
#define Dv  256
#define FFv 512
#define Lv  4
#define BTv (Bv*Tv)
#define EPSv 1e-5f
// Q scale: 1/sqrt(32) * log2(e)  (log2e folded so attn uses raw v_exp_f32 = 2^x)
#define QSC 0.25509402f

typedef __attribute__((ext_vector_type(8))) short short8;
typedef __attribute__((ext_vector_type(4))) float f32x4;
typedef unsigned short us;

#if __has_builtin(__builtin_amdgcn_exp2f)
#define EXP2(x) __builtin_amdgcn_exp2f(x)
#else
#define EXP2(x) exp2f(x)
#endif

// counted vmcnt wait (T4): retire oldest stage, keep newer stages in flight
#define WAITV(n) asm volatile("s_waitcnt vmcnt(" #n ")" ::: "memory")

// single f32 -> bf16 (RNE) via v_cvt_pk_bf16_f32, 1 VALU inst
__device__ __forceinline__ us f2bf(float f) {
    unsigned r;
    asm("v_cvt_pk_bf16_f32 %0, %1, 0" : "=v"(r) : "v"(f));
    return (us)r;
}
// pack two f32 -> 2x bf16 (lo=a, hi=b), 1 VALU inst
__device__ __forceinline__ unsigned pk2(float a, float b) {
    unsigned r;
    asm("v_cvt_pk_bf16_f32 %0, %1, %2" : "=v"(r) : "v"(a), "v"(b));
    return r;
}
__device__ __forceinline__ float wave_sum(float v) {
#pragma unroll
    for (int o = 32; o > 0; o >>= 1) v += __shfl_xor(v, o);
    return v;
}

// ---------------- all weight converts in one launch -------------------------
__global__ __launch_bounds__(256) void cvtall_kernel(
    const float* __restrict__ qw, const float* __restrict__ ow,
    const float* __restrict__ f1, const float* __restrict__ f2,
    const float* __restrict__ qb,
    us* __restrict__ wq, us* __restrict__ wo, us* __restrict__ w1,
    us* __restrict__ w2, float* __restrict__ sb)
{
    int blk = blockIdx.x, tid = threadIdx.x;
    if (blk < 2048) {
        const float* s; us* d; int i; float sc = 1.0f;
        if (blk < 768)       { i = blk*256 + tid;        s = qw; d = wq;
                               sc = (((i >> 6) % 768) < 256) ? QSC : 1.0f; }
        else if (blk < 1024) { i = (blk-768)*256 + tid;  s = ow; d = wo; }
        else if (blk < 1536) { i = (blk-1024)*256 + tid; s = f1; d = w1; }
        else                 { i = (blk-1536)*256 + tid; s = f2; d = w2; }
        float4 v = ((const float4*)s)[i];
        uint2 o;
        o.x = pk2(v.x*sc, v.y*sc);
        o.y = pk2(v.z*sc, v.w*sc);
        ((uint2*)d)[i] = o;
    } else {
        int i = (blk-2048)*256 + tid;
        sb[i] = qb[i] * (((i % 768) < 256) ? QSC : 1.0f);
    }
}

// ---------------- embed + LN: 4 rows/block, one wave per row, float4 --------
__global__ __launch_bounds__(256) void embed_ln_kernel(
    const float* __restrict__ lat, const int* __restrict__ mids,
    const float* __restrict__ pos, const float* __restrict__ ef,
    const float* __restrict__ et,  const float* __restrict__ ep,
    const float* __restrict__ nw,  const float* __restrict__ nb,
    float* __restrict__ x, us* __restrict__ xn)
{
    int wv = threadIdx.x >> 6, lane = threadIdx.x & 63;
    size_t row = (size_t)blockIdx.x * 4 + wv;
    int t  = (int)(row & (Tv - 1));
    int id = mids[row];
    int promo = id >> 12;
    int rem   = id & 4095;
    int frm   = rem >> 6;
    int to    = rem & 63;
    float4 v  = ((const float4*)(lat + row*Dv))[lane];
    float4 pv = ((const float4*)(pos + (size_t)t*Dv))[lane];
    float4 fv = ((const float4*)(ef + (size_t)frm*Dv))[lane];
    float4 tv = ((const float4*)(et + (size_t)to*Dv))[lane];
    float4 ev = ((const float4*)(ep + (size_t)promo*Dv))[lane];
    v.x += pv.x + fv.x + tv.x + ev.x;
    v.y += pv.y + fv.y + tv.y + ev.y;
    v.z += pv.z + fv.z + tv.z + ev.z;
    v.w += pv.w + fv.w + tv.w + ev.w;
    ((float4*)(x + row*Dv))[lane] = v;
    float mu = wave_sum(v.x + v.y + v.z + v.w) * (1.0f/Dv);
    float dx = v.x-mu, dy = v.y-mu, dz = v.z-mu, dw = v.w-mu;
    float var = wave_sum(dx*dx + dy*dy + dz*dz + dw*dw) * (1.0f/Dv);
    float inv = rsqrtf(var + EPSv);
    float4 w4 = ((const float4*)nw)[lane];
    float4 b4 = ((const float4*)nb)[lane];
    uint2 o;
    o.x = pk2(dx*inv*w4.x + b4.x, dy*inv*w4.y + b4.y);
    o.y = pk2(dz*inv*w4.z + b4.z, dw*inv*w4.w + b4.w);
    ((uint2*)(xn + row*Dv))[lane] = o;
}

// ---------------- final: LN + mask select (fp32 out) ------------------------
__global__ __launch_bounds__(256) void final_kernel(
    const float* __restrict__ x, const float* __restrict__ lat,
    const int* __restrict__ mask, const float* __restrict__ w,
    const float* __restrict__ b, float* __restrict__ out)
{
    int wv = threadIdx.x >> 6, lane = threadIdx.x & 63;
    size_t row = (size_t)blockIdx.x * 4 + wv;
    float4 v = ((const float4*)(x + row*Dv))[lane];
    float mu = wave_sum(v.x + v.y + v.z + v.w) * (1.0f/Dv);
    float dx = v.x-mu, dy = v.y-mu, dz = v.z-mu, dw = v.w-mu;
    float var = wave_sum(dx*dx + dy*dy + dz*dz + dw*dw) * (1.0f/Dv);
    float inv = rsqrtf(var + EPSv);
    float4 w4 = ((const float4*)w)[lane];
    float4 b4 = ((const float4*)b)[lane];
    float4 o;
    o.x = dx*inv*w4.x + b4.x;
    o.y = dy*inv*w4.y + b4.y;
    o.z = dz*inv*w4.z + b4.z;
    o.w = dw*inv*w4.w + b4.w;
    if (!mask[row]) o = ((const float4*)(lat + row*Dv))[lane];
    ((float4*)(out + row*Dv))[lane] = o;
}

// ---------------- bf16 MFMA GEMM (128x128 tile, BK=64, XOR-swizzled LDS) ----
// T4 counted-vmcnt 2-deep pipeline (r7). Epilogue: direct scatter stores
// (r8's LDS-transpose epilogue REVERTED: it cost ~8us/dispatch; each wave's
// 2B stores already cover contiguous 32B row-segments, absorbed by L2).
template<int RELU>
__global__ __launch_bounds__(256) void mm_kernel(
    const us* __restrict__ A, const us* __restrict__ B,
    const float* __restrict__ bias, us* __restrict__ C,
    int M, int N, int K)
{
    __shared__ us As[2][128*64];
    __shared__ us Bs[2][128*64];
    int tid  = threadIdx.x;
    int lane = tid & 63;
    int wu   = __builtin_amdgcn_readfirstlane(tid >> 6);
    int m0 = blockIdx.x * 128, n0 = blockIdx.y * 128;
    int wm = wu & 1, wn = wu >> 1;
    f32x4 acc[4][4] = {};
    int srow = lane >> 3;
    int sg   = (lane & 7) ^ srow;
    const us* Ag = A + (size_t)m0 * K + sg*8;
    const us* Bg = B + (size_t)n0 * K + sg*8;
    int cc = lane & 15, q4 = lane >> 4;

#define STG(kk, bb) { \
    _Pragma("unroll") \
    for (int p = 0; p < 4; p++) { \
        int row = wu*32 + p*8; \
        __builtin_amdgcn_global_load_lds( \
            (const __attribute__((address_space(1))) unsigned int*)(Ag + (size_t)(row + srow)*K + (kk)), \
            (__attribute__((address_space(3))) unsigned int*)(&As[bb][row*64]), \
            16, 0, 0); \
        __builtin_amdgcn_global_load_lds( \
            (const __attribute__((address_space(1))) unsigned int*)(Bg + (size_t)(row + srow)*K + (kk)), \
            (__attribute__((address_space(3))) unsigned int*)(&Bs[bb][row*64]), \
            16, 0, 0); \
    } }

    int nk = K >> 6;
    STG(0, 0);
    if (nk > 1) STG(64, 1);
    int cur = 0;
    for (int t = 0; t < nk; t++) {
        if (t < nk - 1) { WAITV(8); } else { WAITV(0); }   // retire stage t only
        __builtin_amdgcn_s_barrier();
        __builtin_amdgcn_sched_barrier(0);
#pragma unroll
        for (int h = 0; h < 2; h++) {
            int pg = ((h*4 + q4) ^ (cc & 7)) * 8;
            short8 av[4], bv[4];
#pragma unroll
            for (int i = 0; i < 4; i++)
                av[i] = *(const short8*)(&As[cur][(wm*64 + i*16 + cc)*64 + pg]);
#pragma unroll
            for (int j = 0; j < 4; j++)
                bv[j] = *(const short8*)(&Bs[cur][(wn*64 + j*16 + cc)*64 + pg]);
#pragma unroll
            for (int i = 0; i < 4; i++)
#pragma unroll
                for (int j = 0; j < 4; j++)
                    acc[i][j] = __builtin_amdgcn_mfma_f32_16x16x32_bf16(av[i], bv[j], acc[i][j], 0, 0, 0);
        }
        __builtin_amdgcn_sched_barrier(0);
        __builtin_amdgcn_s_barrier();
        __builtin_amdgcn_sched_barrier(0);
        if (t + 2 < nk) STG((t+2)*64, cur);                 // refill freed buffer
        cur ^= 1;
    }
#undef STG
#pragma unroll
    for (int j = 0; j < 4; j++) {
        int n = n0 + wn*64 + j*16 + cc;
        float bj = bias[n];
#pragma unroll
        for (int i = 0; i < 4; i++) {
#pragma unroll
            for (int r = 0; r < 4; r++) {
                int m = m0 + wm*64 + i*16 + q4*4 + r;
                float v = acc[i][j][r] + bj;
                if (RELU) v = fmaxf(v, 0.f);
                C[(size_t)m * N + n] = f2bf(v);
            }
        }
    }
}

// ---------------- fused GEMM 128x256 tile + residual + fused LN -------------
// T4 counted-vmcnt 2-deep pipeline (6 loads/stage/thread -> vmcnt(6)).
__global__ __launch_bounds__(512) void mmfuse_kernel(
    const us* __restrict__ A, const us* __restrict__ B,
    const float* __restrict__ bias, float* __restrict__ x,
    us* __restrict__ xn, const float* __restrict__ nw,
    const float* __restrict__ nb, int M, int K)
{
    __shared__ us As[2][128*64];
    __shared__ us Bs[2][256*64];
    __shared__ float red[128][4][2];
    __shared__ float mus[128], rss[128];
    int tid  = threadIdx.x;
    int lane = tid & 63;
    int wu   = __builtin_amdgcn_readfirstlane(tid >> 6);   // 0..7
    int m0 = blockIdx.x * 128;
    int wm = wu & 1, wn = wu >> 1;                          // 2m x 4n waves
    f32x4 acc[4][4] = {};
    int srow = lane >> 3;
    int sg   = (lane & 7) ^ srow;
    const us* Ag = A + (size_t)m0 * K + sg*8;
    const us* Bg = B + sg*8;
    int cc = lane & 15, q4 = lane >> 4;

#define STG(kk, bb) { \
    _Pragma("unroll") \
    for (int p = 0; p < 2; p++) { \
        int row = wu*16 + p*8; \
        __builtin_amdgcn_global_load_lds( \
            (const __attribute__((address_space(1))) unsigned int*)(Ag + (size_t)(row + srow)*K + (kk)), \
            (__attribute__((address_space(3))) unsigned int*)(&As[bb][row*64]), \
            16, 0, 0); \
    } \
    _Pragma("unroll") \
    for (int p = 0; p < 4; p++) { \
        int row = wu*32 + p*8; \
        __builtin_amdgcn_global_load_lds( \
            (const __attribute__((address_space(1))) unsigned int*)(Bg + (size_t)(row + srow)*K + (kk)), \
            (__attribute__((address_space(3))) unsigned int*)(&Bs[bb][row*64]), \
            16, 0, 0); \
    } }

    int nk = K >> 6;
    STG(0, 0);
    if (nk > 1) STG(64, 1);
    int cur = 0;
    for (int t = 0; t < nk; t++) {
        if (t < nk - 1) { WAITV(6); } else { WAITV(0); }
        __builtin_amdgcn_s_barrier();
        __builtin_amdgcn_sched_barrier(0);
#pragma unroll
        for (int h = 0; h < 2; h++) {
            int pg = ((h*4 + q4) ^ (cc & 7)) * 8;
            short8 av[4], bv[4];
#pragma unroll
            for (int i = 0; i < 4; i++)
                av[i] = *(const short8*)(&As[cur][(wm*64 + i*16 + cc)*64 + pg]);
#pragma unroll
            for (int j = 0; j < 4; j++)
                bv[j] = *(const short8*)(&Bs[cur][(wn*64 + j*16 + cc)*64 + pg]);
#pragma unroll
            for (int i = 0; i < 4; i++)
#pragma unroll
                for (int j = 0; j < 4; j++)
                    acc[i][j] = __builtin_amdgcn_mfma_f32_16x16x32_bf16(av[i], bv[j], acc[i][j], 0, 0, 0);
        }
        __builtin_amdgcn_sched_barrier(0);
        __builtin_amdgcn_s_barrier();
        __builtin_amdgcn_sched_barrier(0);
        if (t + 2 < nk) STG((t+2)*64, cur);
        cur ^= 1;
    }
#undef STG

    // ---- epilogue: bias + residual + x write + fused LN -> xn -------------
    float bb4[4], nwv[4], nbv[4];
#pragma unroll
    for (int j = 0; j < 4; j++) {
        int n = wn*64 + j*16 + cc;
        bb4[j] = bias[n]; nwv[j] = nw[n]; nbv[j] = nb[n];
    }
#pragma unroll
    for (int i = 0; i < 4; i++) {
        float s[4] = {0.f,0.f,0.f,0.f}, sq[4] = {0.f,0.f,0.f,0.f};
#pragma unroll
        for (int j = 0; j < 4; j++) {
#pragma unroll
            for (int r = 0; r < 4; r++) {
                int ml = wm*64 + i*16 + q4*4 + r;
                size_t off = (size_t)(m0 + ml) * Dv + wn*64 + j*16 + cc;
                float v = acc[i][j][r] + bb4[j] + x[off];
                acc[i][j][r] = v;
                x[off] = v;
                s[r] += v; sq[r] += v*v;
            }
        }
#pragma unroll
        for (int r = 0; r < 4; r++) {
#pragma unroll
            for (int o = 1; o < 16; o <<= 1) {
                s[r]  += __shfl_xor(s[r],  o);
                sq[r] += __shfl_xor(sq[r], o);
            }
        }
        if (cc == 0) {
#pragma unroll
            for (int r = 0; r < 4; r++) {
                red[wm*64 + i*16 + q4*4 + r][wn][0] = s[r];
                red[wm*64 + i*16 + q4*4 + r][wn][1] = sq[r];
            }
        }
    }
    __syncthreads();
    if (tid < 128) {
        float ts = red[tid][0][0] + red[tid][1][0] + red[tid][2][0] + red[tid][3][0];
        float tq = red[tid][0][1] + red[tid][1][1] + red[tid][2][1] + red[tid][3][1];
        float mu = ts * (1.0f/Dv);
        float var = tq * (1.0f/Dv) - mu*mu;
        mus[tid] = mu;
        rss[tid] = rsqrtf(var + EPSv);
    }
    __syncthreads();
#pragma unroll
    for (int i = 0; i < 4; i++) {
#pragma unroll
        for (int r = 0; r < 4; r++) {
            int ml = wm*64 + i*16 + q4*4 + r;
            float mu = mus[ml], rv = rss[ml];
#pragma unroll
            for (int j = 0; j < 4; j++) {
                size_t off = (size_t)(m0 + ml) * Dv + wn*64 + j*16 + cc;
                xn[off] = f2bf((acc[i][j][r] - mu)*rv*nwv[j] + nbv[j]);
            }
        }
    }
}

// ---------------- MFMA flash attention (S^T form, 2-deep pipelined) ---------
// Q pre-scaled by 1/sqrt(32)*log2e -> softmax numerator = exp2(s).
// Diag-tile skip: wave wu only needs key sub-tiles jt <= wu (block-causal);
// jt > wu are fully masked -> skip QK MFMA + exp, zero-fill Ps; lane mask
// applied only at jt == wu; PV kk=1 skipped when its P rows are all zero.
__global__ __launch_bounds__(256) void attn_kernel(
    const us* __restrict__ qkv, us* __restrict__ ao)
{
    int blk = blockIdx.x;
    int b  = blk & 63;
    int h  = (blk >> 6) & 7;
    int qt = blk >> 9;
    int i0 = qt << 6;
    int tid = threadIdx.x;
    int lane = tid & 63;
    int wu = tid >> 6;

    __shared__ us Ks[2][64][40];
    __shared__ us Vt[2][32][72];
    __shared__ us Ps[4][16][72];
    __shared__ float Ls[4][16];

    size_t rowbase = (size_t)b * Tv;
    int c = lane & 15, q4 = lane >> 4;

    short8 qfrag = *(const short8*)(qkv + (rowbase + i0 + wu*16 + c)*768 + h*32 + q4*8);

    int skey = tid >> 2, sdc = (tid & 3) << 3;
    int vkey = tid & 63, vg = tid >> 6;
    const us* kgp = qkv + (rowbase + skey)*768 + 256 + h*32 + sdc;
    const us* vgp = qkv + (rowbase + vkey)*768 + 512 + h*32 + vg*8;

    f32x4 oacc[2] = {};
    float lsum = 0.f;
    int ntiles = qt + 1;

    short8 kreg = *(const short8*)(kgp);
    short8 vreg = *(const short8*)(vgp);
    *(short8*)&Ks[0][skey][sdc] = kreg;
#pragma unroll
    for (int j = 0; j < 8; j++) Vt[0][vg*8 + j][vkey] = vreg[j];
    if (ntiles > 1) {
        kreg = *(const short8*)(kgp + 64*768);
        vreg = *(const short8*)(vgp + 64*768);
    }
    __syncthreads();

    for (int kt = 0; kt < ntiles; kt++) {
        int cur = kt & 1;
        if (kt + 1 < ntiles) {
            *(short8*)&Ks[cur^1][skey][sdc] = kreg;
#pragma unroll
            for (int j = 0; j < 8; j++) Vt[cur^1][vg*8 + j][vkey] = vreg[j];
        }
        if (kt + 2 < ntiles) {
            kreg = *(const short8*)(kgp + (size_t)(kt+2)*64*768);
            vreg = *(const short8*)(vgp + (size_t)(kt+2)*64*768);
        }

        bool diag = (kt == ntiles - 1);
        int jtend = diag ? (wu + 1) : 4;      // wave-uniform
        f32x4 st[4];
#pragma unroll
        for (int jt = 0; jt < 4; jt++) {
            if (jt < jtend) {
                short8 kf = *(const short8*)&Ks[cur][jt*16 + c][q4*8];
                st[jt] = __builtin_amdgcn_mfma_f32_16x16x32_bf16(kf, qfrag, (f32x4){0.f,0.f,0.f,0.f}, 0, 0, 0);
            }
        }
#pragma unroll
        for (int jt = 0; jt < 4; jt++) {
            if (jt < jtend) {
                float msk = (diag && jt == wu) ? (((q4 >> 1) <= (c >> 3)) ? 1.f : 0.f) : 1.f;
                float p0 = EXP2(st[jt][0]) * msk;
                float p1 = EXP2(st[jt][1]) * msk;
                float p2 = EXP2(st[jt][2]) * msk;
                float p3 = EXP2(st[jt][3]) * msk;
                lsum += p0 + p1 + p2 + p3;
                uint2 w2; w2.x = pk2(p0, p1); w2.y = pk2(p2, p3);
                *(uint2*)&Ps[wu][c][jt*16 + q4*4] = w2;
            } else {
                uint2 z; z.x = 0u; z.y = 0u;
                *(uint2*)&Ps[wu][c][jt*16 + q4*4] = z;
            }
        }
        int kkend = (diag && wu < 2) ? 1 : 2; // P rows for kk=1 all zero
#pragma unroll
        for (int kk = 0; kk < 2; kk++) {
            if (kk < kkend) {
                short8 pf = *(const short8*)&Ps[wu][c][kk*32 + q4*8];
#pragma unroll
                for (int dt = 0; dt < 2; dt++) {
                    short8 vf = *(const short8*)&Vt[cur][dt*16 + c][kk*32 + q4*8];
                    oacc[dt] = __builtin_amdgcn_mfma_f32_16x16x32_bf16(pf, vf, oacc[dt], 0, 0, 0);
                }
            }
        }
        __syncthreads();
    }

    float l = lsum;
    l += __shfl_xor(l, 16);
    l += __shfl_xor(l, 32);
    if (q4 == 0) Ls[wu][c] = 1.0f / l;
    float4 lv4 = *(const float4*)&Ls[wu][q4*4];
#pragma unroll
    for (int dt = 0; dt < 2; dt++) {
#pragma unroll
        for (int r = 0; r < 4; r++) {
            float li = (r == 0) ? lv4.x : (r == 1) ? lv4.y : (r == 2) ? lv4.z : lv4.w;
            ao[(rowbase + i0 + wu*16 + q4*4 + r)*256 + h*32 + dt*16 + c] = f2bf(oacc[dt][r] * li);
        }
    }
}

// ---------------- launch ----------------------------------------------------
extern "C" void kernel_launch(void* const* d_in, const int* in_sizes, int n_in,
                              void* d_out, int out_size, void* d_ws, size_t ws_size,
                              hipStream_t stream)
{
    const float* latents    = (const float*)d_in[0];
    const int*   move_ids   = (const int*)  d_in[1];
    const int*   mask       = (const int*)  d_in[2];
    const float* positional = (const float*)d_in[3];
    const float* embed_from = (const float*)d_in[4];
    const float* embed_to   = (const float*)d_in[5];
    const float* embed_promo= (const float*)d_in[6];
    const float* in_proj_w  = (const float*)d_in[7];
    const float* in_proj_b  = (const float*)d_in[8];
    const float* out_w      = (const float*)d_in[9];
    const float* out_b      = (const float*)d_in[10];
    const float* fc1_w      = (const float*)d_in[11];
    const float* fc1_b      = (const float*)d_in[12];
    const float* fc2_w      = (const float*)d_in[13];
    const float* fc2_b      = (const float*)d_in[14];
    const float* norm_w     = (const float*)d_in[15];
    const float* norm_b     = (const float*)d_in[16];
    float* out = (float*)d_out;

    float* x   = (float*)d_ws;                              // BT*256 f32
    float* sb  = x + (size_t)BTv * Dv;                      // L*768 f32
    us* xn  = (us*)(sb + Lv*768);                           // BT*256 bf16
    us* qkv = xn + (size_t)BTv * Dv;                        // BT*768
    us* ao  = qkv + (size_t)BTv * 768;                      // BT*256
    us* h1  = ao + (size_t)BTv * Dv;                        // BT*512 bf16 (ffn intermediate)
    us* wq  = h1 + (size_t)BTv * FFv;                       // L*768*256
    us* wo  = wq + (size_t)Lv * 768 * Dv;
    us* w1  = wo + (size_t)Lv * Dv * Dv;
    us* w2  = w1 + (size_t)Lv * FFv * Dv;

    cvtall_kernel<<<2060, 256, 0, stream>>>(in_proj_w, out_w, fc1_w, fc2_w,
                                            in_proj_b, wq, wo, w1, w2, sb);

    embed_ln_kernel<<<BTv/4, 256, 0, stream>>>(latents, move_ids, positional,
        embed_from, embed_to, embed_promo, norm_w, norm_b, x, xn);

    for (int l = 0; l < Lv; l++) {
        // QKV: 128^2 tile, counted-vmcnt pipeline
        mm_kernel<0><<<dim3(BTv/128, 768/128), 256, 0, stream>>>(
            xn, wq + (size_t)l*768*Dv, sb + l*768, qkv, BTv, 768, Dv);
        attn_kernel<<<Bv*8*(Tv/64), 256, 0, stream>>>(qkv, ao);
        // attn-out proj + residual + LN (K=256)
        mmfuse_kernel<<<BTv/128, 512, 0, stream>>>(
            ao, wo + (size_t)l*Dv*Dv, out_b + l*Dv, x, xn, norm_w, norm_b,
            BTv, Dv);
        // FFN phase 1: h1 = relu(xn @ W1^T + b1)
        mm_kernel<1><<<dim3(BTv/128, FFv/128), 256, 0, stream>>>(
            xn, w1 + (size_t)l*FFv*Dv, fc1_b + l*FFv, h1, BTv, FFv, Dv);
        // FFN phase 2: x += h1 @ W2^T + b2 ; xn = LN(x)  (K=512)
        mmfuse_kernel<<<BTv/128, 512, 0, stream>>>(
            h1, w2 + (size_t)l*Dv*FFv, fc2_b + l*Dv, x, xn, norm_w, norm_b,
            BTv, FFv);
    }
    final_kernel<<<BTv/4, 256, 0, stream>>>(x, latents, mask, norm_w, norm_b, out);
}

// Round 10
// 605.624 us; speedup vs baseline: 1.1195x; 1.0186x over previous
//
#include <hip/hip_runtime.h>
#include <math.h>

#define Bv  64
#define Tv  512
#define Dv  256
#define FFv 512
#define Lv  4
#define BTv (Bv*Tv)
#define EPSv 1e-5f
// Q scale: 1/sqrt(32) * log2(e)  (log2e folded so attn uses raw v_exp_f32 = 2^x)
#define QSC 0.25509402f

typedef __attribute__((ext_vector_type(8))) short short8;
typedef __attribute__((ext_vector_type(4))) float f32x4;
typedef unsigned short us;

#if __has_builtin(__builtin_amdgcn_exp2f)
#define EXP2(x) __builtin_amdgcn_exp2f(x)
#else
#define EXP2(x) exp2f(x)
#endif

// counted vmcnt wait (T4): retire oldest stage, keep newer stages in flight
#define WAITV(n) asm volatile("s_waitcnt vmcnt(" #n ")" ::: "memory")

// single f32 -> bf16 (RNE) via v_cvt_pk_bf16_f32, 1 VALU inst
__device__ __forceinline__ us f2bf(float f) {
    unsigned r;
    asm("v_cvt_pk_bf16_f32 %0, %1, 0" : "=v"(r) : "v"(f));
    return (us)r;
}
// pack two f32 -> 2x bf16 (lo=a, hi=b), 1 VALU inst
__device__ __forceinline__ unsigned pk2(float a, float b) {
    unsigned r;
    asm("v_cvt_pk_bf16_f32 %0, %1, %2" : "=v"(r) : "v"(a), "v"(b));
    return r;
}
__device__ __forceinline__ float wave_sum(float v) {
#pragma unroll
    for (int o = 32; o > 0; o >>= 1) v += __shfl_xor(v, o);
    return v;
}

// ---------------- all weight converts in one launch -------------------------
__global__ __launch_bounds__(256) void cvtall_kernel(
    const float* __restrict__ qw, const float* __restrict__ ow,
    const float* __restrict__ f1, const float* __restrict__ f2,
    const float* __restrict__ qb,
    us* __restrict__ wq, us* __restrict__ wo, us* __restrict__ w1,
    us* __restrict__ w2, float* __restrict__ sb)
{
    int blk = blockIdx.x, tid = threadIdx.x;
    if (blk < 2048) {
        const float* s; us* d; int i; float sc = 1.0f;
        if (blk < 768)       { i = blk*256 + tid;        s = qw; d = wq;
                               sc = (((i >> 6) % 768) < 256) ? QSC : 1.0f; }
        else if (blk < 1024) { i = (blk-768)*256 + tid;  s = ow; d = wo; }
        else if (blk < 1536) { i = (blk-1024)*256 + tid; s = f1; d = w1; }
        else                 { i = (blk-1536)*256 + tid; s = f2; d = w2; }
        float4 v = ((const float4*)s)[i];
        uint2 o;
        o.x = pk2(v.x*sc, v.y*sc);
        o.y = pk2(v.z*sc, v.w*sc);
        ((uint2*)d)[i] = o;
    } else {
        int i = (blk-2048)*256 + tid;
        sb[i] = qb[i] * (((i % 768) < 256) ? QSC : 1.0f);
    }
}

// ---------------- embed + LN: 4 rows/block, one wave per row, float4 --------
__global__ __launch_bounds__(256) void embed_ln_kernel(
    const float* __restrict__ lat, const int* __restrict__ mids,
    const float* __restrict__ pos, const float* __restrict__ ef,
    const float* __restrict__ et,  const float* __restrict__ ep,
    const float* __restrict__ nw,  const float* __restrict__ nb,
    float* __restrict__ x, us* __restrict__ xn)
{
    int wv = threadIdx.x >> 6, lane = threadIdx.x & 63;
    size_t row = (size_t)blockIdx.x * 4 + wv;
    int t  = (int)(row & (Tv - 1));
    int id = mids[row];
    int promo = id >> 12;
    int rem   = id & 4095;
    int frm   = rem >> 6;
    int to    = rem & 63;
    float4 v  = ((const float4*)(lat + row*Dv))[lane];
    float4 pv = ((const float4*)(pos + (size_t)t*Dv))[lane];
    float4 fv = ((const float4*)(ef + (size_t)frm*Dv))[lane];
    float4 tv = ((const float4*)(et + (size_t)to*Dv))[lane];
    float4 ev = ((const float4*)(ep + (size_t)promo*Dv))[lane];
    v.x += pv.x + fv.x + tv.x + ev.x;
    v.y += pv.y + fv.y + tv.y + ev.y;
    v.z += pv.z + fv.z + tv.z + ev.z;
    v.w += pv.w + fv.w + tv.w + ev.w;
    ((float4*)(x + row*Dv))[lane] = v;
    float mu = wave_sum(v.x + v.y + v.z + v.w) * (1.0f/Dv);
    float dx = v.x-mu, dy = v.y-mu, dz = v.z-mu, dw = v.w-mu;
    float var = wave_sum(dx*dx + dy*dy + dz*dz + dw*dw) * (1.0f/Dv);
    float inv = rsqrtf(var + EPSv);
    float4 w4 = ((const float4*)nw)[lane];
    float4 b4 = ((const float4*)nb)[lane];
    uint2 o;
    o.x = pk2(dx*inv*w4.x + b4.x, dy*inv*w4.y + b4.y);
    o.y = pk2(dz*inv*w4.z + b4.z, dw*inv*w4.w + b4.w);
    ((uint2*)(xn + row*Dv))[lane] = o;
}

// ---------------- final: LN + mask select (fp32 out) ------------------------
__global__ __launch_bounds__(256) void final_kernel(
    const float* __restrict__ x, const float* __restrict__ lat,
    const int* __restrict__ mask, const float* __restrict__ w,
    const float* __restrict__ b, float* __restrict__ out)
{
    int wv = threadIdx.x >> 6, lane = threadIdx.x & 63;
    size_t row = (size_t)blockIdx.x * 4 + wv;
    float4 v = ((const float4*)(x + row*Dv))[lane];
    float mu = wave_sum(v.x + v.y + v.z + v.w) * (1.0f/Dv);
    float dx = v.x-mu, dy = v.y-mu, dz = v.z-mu, dw = v.w-mu;
    float var = wave_sum(dx*dx + dy*dy + dz*dz + dw*dw) * (1.0f/Dv);
    float inv = rsqrtf(var + EPSv);
    float4 w4 = ((const float4*)w)[lane];
    float4 b4 = ((const float4*)b)[lane];
    float4 o;
    o.x = dx*inv*w4.x + b4.x;
    o.y = dy*inv*w4.y + b4.y;
    o.z = dz*inv*w4.z + b4.z;
    o.w = dw*inv*w4.w + b4.w;
    if (!mask[row]) o = ((const float4*)(lat + row*Dv))[lane];
    ((float4*)(out + row*Dv))[lane] = o;
}

// ---------------- bf16 MFMA GEMM (128x128 tile, BK=64, XOR-swizzled LDS) ----
// T4 counted-vmcnt 2-deep pipeline (r7). Direct scatter-store epilogue.
template<int RELU>
__global__ __launch_bounds__(256) void mm_kernel(
    const us* __restrict__ A, const us* __restrict__ B,
    const float* __restrict__ bias, us* __restrict__ C,
    int M, int N, int K)
{
    __shared__ us As[2][128*64];
    __shared__ us Bs[2][128*64];
    int tid  = threadIdx.x;
    int lane = tid & 63;
    int wu   = __builtin_amdgcn_readfirstlane(tid >> 6);
    int m0 = blockIdx.x * 128, n0 = blockIdx.y * 128;
    int wm = wu & 1, wn = wu >> 1;
    f32x4 acc[4][4] = {};
    int srow = lane >> 3;
    int sg   = (lane & 7) ^ srow;
    const us* Ag = A + (size_t)m0 * K + sg*8;
    const us* Bg = B + (size_t)n0 * K + sg*8;
    int cc = lane & 15, q4 = lane >> 4;

#define STG(kk, bb) { \
    _Pragma("unroll") \
    for (int p = 0; p < 4; p++) { \
        int row = wu*32 + p*8; \
        __builtin_amdgcn_global_load_lds( \
            (const __attribute__((address_space(1))) unsigned int*)(Ag + (size_t)(row + srow)*K + (kk)), \
            (__attribute__((address_space(3))) unsigned int*)(&As[bb][row*64]), \
            16, 0, 0); \
        __builtin_amdgcn_global_load_lds( \
            (const __attribute__((address_space(1))) unsigned int*)(Bg + (size_t)(row + srow)*K + (kk)), \
            (__attribute__((address_space(3))) unsigned int*)(&Bs[bb][row*64]), \
            16, 0, 0); \
    } }

    int nk = K >> 6;
    STG(0, 0);
    if (nk > 1) STG(64, 1);
    int cur = 0;
    for (int t = 0; t < nk; t++) {
        if (t < nk - 1) { WAITV(8); } else { WAITV(0); }   // retire stage t only
        __builtin_amdgcn_s_barrier();
        __builtin_amdgcn_sched_barrier(0);
#pragma unroll
        for (int h = 0; h < 2; h++) {
            int pg = ((h*4 + q4) ^ (cc & 7)) * 8;
            short8 av[4], bv[4];
#pragma unroll
            for (int i = 0; i < 4; i++)
                av[i] = *(const short8*)(&As[cur][(wm*64 + i*16 + cc)*64 + pg]);
#pragma unroll
            for (int j = 0; j < 4; j++)
                bv[j] = *(const short8*)(&Bs[cur][(wn*64 + j*16 + cc)*64 + pg]);
#pragma unroll
            for (int i = 0; i < 4; i++)
#pragma unroll
                for (int j = 0; j < 4; j++)
                    acc[i][j] = __builtin_amdgcn_mfma_f32_16x16x32_bf16(av[i], bv[j], acc[i][j], 0, 0, 0);
        }
        __builtin_amdgcn_sched_barrier(0);
        __builtin_amdgcn_s_barrier();
        __builtin_amdgcn_sched_barrier(0);
        if (t + 2 < nk) STG((t+2)*64, cur);                 // refill freed buffer
        cur ^= 1;
    }
#undef STG
#pragma unroll
    for (int j = 0; j < 4; j++) {
        int n = n0 + wn*64 + j*16 + cc;
        float bj = bias[n];
#pragma unroll
        for (int i = 0; i < 4; i++) {
#pragma unroll
            for (int r = 0; r < 4; r++) {
                int m = m0 + wm*64 + i*16 + q4*4 + r;
                float v = acc[i][j][r] + bj;
                if (RELU) v = fmaxf(v, 0.f);
                C[(size_t)m * N + n] = f2bf(v);
            }
        }
    }
}

// ---------------- fused GEMM 128x256 tile + residual + fused LN -------------
// T4 counted-vmcnt pipeline. r10: the residual tile (64 f32/thread) is
// PREFETCHED into registers BEFORE the K-loop (oldest in vmcnt queue ->
// complete before the counted window matters; sched_barrier pins placement),
// so the epilogue is pure register compute + stores instead of 64 dependent
// scattered loads at 1 block/CU. __launch_bounds__(512,2) lifts the VGPR cap
// to 256 (free at 1 block/CU) so the compiler keeps all 64 values live.
__global__ __launch_bounds__(512, 2) void mmfuse_kernel(
    const us* __restrict__ A, const us* __restrict__ B,
    const float* __restrict__ bias, float* __restrict__ x,
    us* __restrict__ xn, const float* __restrict__ nw,
    const float* __restrict__ nb, int M, int K)
{
    __shared__ us As[2][128*64];
    __shared__ us Bs[2][256*64];
    __shared__ float red[128][4][2];
    __shared__ float mus[128], rss[128];
    int tid  = threadIdx.x;
    int lane = tid & 63;
    int wu   = __builtin_amdgcn_readfirstlane(tid >> 6);   // 0..7
    int m0 = blockIdx.x * 128;
    int wm = wu & 1, wn = wu >> 1;                          // 2m x 4n waves
    f32x4 acc[4][4] = {};
    int srow = lane >> 3;
    int sg   = (lane & 7) ^ srow;
    const us* Ag = A + (size_t)m0 * K + sg*8;
    const us* Bg = B + sg*8;
    int cc = lane & 15, q4 = lane >> 4;

    // ---- prefetch: residual x tile + bias/LN params -> regs (issued FIRST,
    // oldest in vmcnt queue; done long before the epilogue needs them) ------
    float xr[4][4][4];
    float bb4[4], nwv[4], nbv[4];
#pragma unroll
    for (int i = 0; i < 4; i++)
#pragma unroll
        for (int j = 0; j < 4; j++)
#pragma unroll
            for (int r = 0; r < 4; r++) {
                int ml = wm*64 + i*16 + q4*4 + r;
                xr[i][j][r] = x[(size_t)(m0 + ml) * Dv + wn*64 + j*16 + cc];
            }
#pragma unroll
    for (int j = 0; j < 4; j++) {
        int n = wn*64 + j*16 + cc;
        bb4[j] = bias[n]; nwv[j] = nw[n]; nbv[j] = nb[n];
    }
    __builtin_amdgcn_sched_barrier(0);   // pin prefetch issue before K-loop

#define STG(kk, bb) { \
    _Pragma("unroll") \
    for (int p = 0; p < 2; p++) { \
        int row = wu*16 + p*8; \
        __builtin_amdgcn_global_load_lds( \
            (const __attribute__((address_space(1))) unsigned int*)(Ag + (size_t)(row + srow)*K + (kk)), \
            (__attribute__((address_space(3))) unsigned int*)(&As[bb][row*64]), \
            16, 0, 0); \
    } \
    _Pragma("unroll") \
    for (int p = 0; p < 4; p++) { \
        int row = wu*32 + p*8; \
        __builtin_amdgcn_global_load_lds( \
            (const __attribute__((address_space(1))) unsigned int*)(Bg + (size_t)(row + srow)*K + (kk)), \
            (__attribute__((address_space(3))) unsigned int*)(&Bs[bb][row*64]), \
            16, 0, 0); \
    } }

    int nk = K >> 6;
    STG(0, 0);
    if (nk > 1) STG(64, 1);
    int cur = 0;
    for (int t = 0; t < nk; t++) {
        if (t < nk - 1) { WAITV(6); } else { WAITV(0); }
        __builtin_amdgcn_s_barrier();
        __builtin_amdgcn_sched_barrier(0);
#pragma unroll
        for (int h = 0; h < 2; h++) {
            int pg = ((h*4 + q4) ^ (cc & 7)) * 8;
            short8 av[4], bv[4];
#pragma unroll
            for (int i = 0; i < 4; i++)
                av[i] = *(const short8*)(&As[cur][(wm*64 + i*16 + cc)*64 + pg]);
#pragma unroll
            for (int j = 0; j < 4; j++)
                bv[j] = *(const short8*)(&Bs[cur][(wn*64 + j*16 + cc)*64 + pg]);
#pragma unroll
            for (int i = 0; i < 4; i++)
#pragma unroll
                for (int j = 0; j < 4; j++)
                    acc[i][j] = __builtin_amdgcn_mfma_f32_16x16x32_bf16(av[i], bv[j], acc[i][j], 0, 0, 0);
        }
        __builtin_amdgcn_sched_barrier(0);
        __builtin_amdgcn_s_barrier();
        __builtin_amdgcn_sched_barrier(0);
        if (t + 2 < nk) STG((t+2)*64, cur);
        cur ^= 1;
    }
#undef STG

    // ---- epilogue: bias + residual (regs) + x write + fused LN -> xn ------
#pragma unroll
    for (int i = 0; i < 4; i++) {
        float s[4] = {0.f,0.f,0.f,0.f}, sq[4] = {0.f,0.f,0.f,0.f};
#pragma unroll
        for (int j = 0; j < 4; j++) {
#pragma unroll
            for (int r = 0; r < 4; r++) {
                int ml = wm*64 + i*16 + q4*4 + r;
                size_t off = (size_t)(m0 + ml) * Dv + wn*64 + j*16 + cc;
                float v = acc[i][j][r] + bb4[j] + xr[i][j][r];
                acc[i][j][r] = v;
                x[off] = v;
                s[r] += v; sq[r] += v*v;
            }
        }
#pragma unroll
        for (int r = 0; r < 4; r++) {
#pragma unroll
            for (int o = 1; o < 16; o <<= 1) {
                s[r]  += __shfl_xor(s[r],  o);
                sq[r] += __shfl_xor(sq[r], o);
            }
        }
        if (cc == 0) {
#pragma unroll
            for (int r = 0; r < 4; r++) {
                red[wm*64 + i*16 + q4*4 + r][wn][0] = s[r];
                red[wm*64 + i*16 + q4*4 + r][wn][1] = sq[r];
            }
        }
    }
    __syncthreads();
    if (tid < 128) {
        float ts = red[tid][0][0] + red[tid][1][0] + red[tid][2][0] + red[tid][3][0];
        float tq = red[tid][0][1] + red[tid][1][1] + red[tid][2][1] + red[tid][3][1];
        float mu = ts * (1.0f/Dv);
        float var = tq * (1.0f/Dv) - mu*mu;
        mus[tid] = mu;
        rss[tid] = rsqrtf(var + EPSv);
    }
    __syncthreads();
#pragma unroll
    for (int i = 0; i < 4; i++) {
#pragma unroll
        for (int r = 0; r < 4; r++) {
            int ml = wm*64 + i*16 + q4*4 + r;
            float mu = mus[ml], rv = rss[ml];
#pragma unroll
            for (int j = 0; j < 4; j++) {
                size_t off = (size_t)(m0 + ml) * Dv + wn*64 + j*16 + cc;
                xn[off] = f2bf((acc[i][j][r] - mu)*rv*nwv[j] + nbv[j]);
            }
        }
    }
}

// ---------------- MFMA flash attention (S^T form, 2-deep pipelined) ---------
// Q pre-scaled by 1/sqrt(32)*log2e -> softmax numerator = exp2(s).
// Diag-tile skip: wave wu only needs key sub-tiles jt <= wu (block-causal);
// jt > wu are fully masked -> skip QK MFMA + exp, zero-fill Ps; lane mask
// applied only at jt == wu; PV kk=1 skipped when its P rows are all zero.
__global__ __launch_bounds__(256) void attn_kernel(
    const us* __restrict__ qkv, us* __restrict__ ao)
{
    int blk = blockIdx.x;
    int b  = blk & 63;
    int h  = (blk >> 6) & 7;
    int qt = blk >> 9;
    int i0 = qt << 6;
    int tid = threadIdx.x;
    int lane = tid & 63;
    int wu = tid >> 6;

    __shared__ us Ks[2][64][40];
    __shared__ us Vt[2][32][72];
    __shared__ us Ps[4][16][72];
    __shared__ float Ls[4][16];

    size_t rowbase = (size_t)b * Tv;
    int c = lane & 15, q4 = lane >> 4;

    short8 qfrag = *(const short8*)(qkv + (rowbase + i0 + wu*16 + c)*768 + h*32 + q4*8);

    int skey = tid >> 2, sdc = (tid & 3) << 3;
    int vkey = tid & 63, vg = tid >> 6;
    const us* kgp = qkv + (rowbase + skey)*768 + 256 + h*32 + sdc;
    const us* vgp = qkv + (rowbase + vkey)*768 + 512 + h*32 + vg*8;

    f32x4 oacc[2] = {};
    float lsum = 0.f;
    int ntiles = qt + 1;

    short8 kreg = *(const short8*)(kgp);
    short8 vreg = *(const short8*)(vgp);
    *(short8*)&Ks[0][skey][sdc] = kreg;
#pragma unroll
    for (int j = 0; j < 8; j++) Vt[0][vg*8 + j][vkey] = vreg[j];
    if (ntiles > 1) {
        kreg = *(const short8*)(kgp + 64*768);
        vreg = *(const short8*)(vgp + 64*768);
    }
    __syncthreads();

    for (int kt = 0; kt < ntiles; kt++) {
        int cur = kt & 1;
        if (kt + 1 < ntiles) {
            *(short8*)&Ks[cur^1][skey][sdc] = kreg;
#pragma unroll
            for (int j = 0; j < 8; j++) Vt[cur^1][vg*8 + j][vkey] = vreg[j];
        }
        if (kt + 2 < ntiles) {
            kreg = *(const short8*)(kgp + (size_t)(kt+2)*64*768);
            vreg = *(const short8*)(vgp + (size_t)(kt+2)*64*768);
        }

        bool diag = (kt == ntiles - 1);
        int jtend = diag ? (wu + 1) : 4;      // wave-uniform
        f32x4 st[4];
#pragma unroll
        for (int jt = 0; jt < 4; jt++) {
            if (jt < jtend) {
                short8 kf = *(const short8*)&Ks[cur][jt*16 + c][q4*8];
                st[jt] = __builtin_amdgcn_mfma_f32_16x16x32_bf16(kf, qfrag, (f32x4){0.f,0.f,0.f,0.f}, 0, 0, 0);
            }
        }
#pragma unroll
        for (int jt = 0; jt < 4; jt++) {
            if (jt < jtend) {
                float msk = (diag && jt == wu) ? (((q4 >> 1) <= (c >> 3)) ? 1.f : 0.f) : 1.f;
                float p0 = EXP2(st[jt][0]) * msk;
                float p1 = EXP2(st[jt][1]) * msk;
                float p2 = EXP2(st[jt][2]) * msk;
                float p3 = EXP2(st[jt][3]) * msk;
                lsum += p0 + p1 + p2 + p3;
                uint2 w2; w2.x = pk2(p0, p1); w2.y = pk2(p2, p3);
                *(uint2*)&Ps[wu][c][jt*16 + q4*4] = w2;
            } else {
                uint2 z; z.x = 0u; z.y = 0u;
                *(uint2*)&Ps[wu][c][jt*16 + q4*4] = z;
            }
        }
        int kkend = (diag && wu < 2) ? 1 : 2; // P rows for kk=1 all zero
#pragma unroll
        for (int kk = 0; kk < 2; kk++) {
            if (kk < kkend) {
                short8 pf = *(const short8*)&Ps[wu][c][kk*32 + q4*8];
#pragma unroll
                for (int dt = 0; dt < 2; dt++) {
                    short8 vf = *(const short8*)&Vt[cur][dt*16 + c][kk*32 + q4*8];
                    oacc[dt] = __builtin_amdgcn_mfma_f32_16x16x32_bf16(pf, vf, oacc[dt], 0, 0, 0);
                }
            }
        }
        __syncthreads();
    }

    float l = lsum;
    l += __shfl_xor(l, 16);
    l += __shfl_xor(l, 32);
    if (q4 == 0) Ls[wu][c] = 1.0f / l;
    float4 lv4 = *(const float4*)&Ls[wu][q4*4];
#pragma unroll
    for (int dt = 0; dt < 2; dt++) {
#pragma unroll
        for (int r = 0; r < 4; r++) {
            float li = (r == 0) ? lv4.x : (r == 1) ? lv4.y : (r == 2) ? lv4.z : lv4.w;
            ao[(rowbase + i0 + wu*16 + q4*4 + r)*256 + h*32 + dt*16 + c] = f2bf(oacc[dt][r] * li);
        }
    }
}

// ---------------- launch ----------------------------------------------------
extern "C" void kernel_launch(void* const* d_in, const int* in_sizes, int n_in,
                              void* d_out, int out_size, void* d_ws, size_t ws_size,
                              hipStream_t stream)
{
    const float* latents    = (const float*)d_in[0];
    const int*   move_ids   = (const int*)  d_in[1];
    const int*   mask       = (const int*)  d_in[2];
    const float* positional = (const float*)d_in[3];
    const float* embed_from = (const float*)d_in[4];
    const float* embed_to   = (const float*)d_in[5];
    const float* embed_promo= (const float*)d_in[6];
    const float* in_proj_w  = (const float*)d_in[7];
    const float* in_proj_b  = (const float*)d_in[8];
    const float* out_w      = (const float*)d_in[9];
    const float* out_b      = (const float*)d_in[10];
    const float* fc1_w      = (const float*)d_in[11];
    const float* fc1_b      = (const float*)d_in[12];
    const float* fc2_w      = (const float*)d_in[13];
    const float* fc2_b      = (const float*)d_in[14];
    const float* norm_w     = (const float*)d_in[15];
    const float* norm_b     = (const float*)d_in[16];
    float* out = (float*)d_out;

    float* x   = (float*)d_ws;                              // BT*256 f32
    float* sb  = x + (size_t)BTv * Dv;                      // L*768 f32
    us* xn  = (us*)(sb + Lv*768);                           // BT*256 bf16
    us* qkv = xn + (size_t)BTv * Dv;                        // BT*768
    us* ao  = qkv + (size_t)BTv * 768;                      // BT*256
    us* h1  = ao + (size_t)BTv * Dv;                        // BT*512 bf16 (ffn intermediate)
    us* wq  = h1 + (size_t)BTv * FFv;                       // L*768*256
    us* wo  = wq + (size_t)Lv * 768 * Dv;
    us* w1  = wo + (size_t)Lv * Dv * Dv;
    us* w2  = w1 + (size_t)Lv * FFv * Dv;

    cvtall_kernel<<<2060, 256, 0, stream>>>(in_proj_w, out_w, fc1_w, fc2_w,
                                            in_proj_b, wq, wo, w1, w2, sb);

    embed_ln_kernel<<<BTv/4, 256, 0, stream>>>(latents, move_ids, positional,
        embed_from, embed_to, embed_promo, norm_w, norm_b, x, xn);

    for (int l = 0; l < Lv; l++) {
        // QKV: 128^2 tile, counted-vmcnt pipeline
        mm_kernel<0><<<dim3(BTv/128, 768/128), 256, 0, stream>>>(
            xn, wq + (size_t)l*768*Dv, sb + l*768, qkv, BTv, 768, Dv);
        attn_kernel<<<Bv*8*(Tv/64), 256, 0, stream>>>(qkv, ao);
        // attn-out proj + residual + LN (K=256)
        mmfuse_kernel<<<BTv/128, 512, 0, stream>>>(
            ao, wo + (size_t)l*Dv*Dv, out_b + l*Dv, x, xn, norm_w, norm_b,
            BTv, Dv);
        // FFN phase 1: h1 = relu(xn @ W1^T + b1)
        mm_kernel<1><<<dim3(BTv/128, FFv/128), 256, 0, stream>>>(
            xn, w1 + (size_t)l*FFv*Dv, fc1_b + l*FFv, h1, BTv, FFv, Dv);
        // FFN phase 2: x += h1 @ W2^T + b2 ; xn = LN(x)  (K=512)
        mmfuse_kernel<<<BTv/128, 512, 0, stream>>>(
            h1, w2 + (size_t)l*Dv*FFv, fc2_b + l*Dv, x, xn, norm_w, norm_b,
            BTv, FFv);
    }
    final_kernel<<<BTv/4, 256, 0, stream>>>(x, latents, mask, norm_w, norm_b, out);
}

// Round 11
// 603.342 us; speedup vs baseline: 1.1237x; 1.0038x over previous
//
#include <hip/hip_runtime.h>
#include <math.h>

#define Bv  64
#define Tv  512
#define Dv  256
#define FFv 512
#define Lv  4
#define BTv (Bv*Tv)
#define EPSv 1e-5f
// Q scale: 1/sqrt(32) * log2(e)  (log2e folded so attn uses raw v_exp_f32 = 2^x)
#define QSC 0.25509402f

typedef __attribute__((ext_vector_type(8))) short short8;
typedef __attribute__((ext_vector_type(4))) float f32x4;
typedef unsigned short us;

#if __has_builtin(__builtin_amdgcn_exp2f)
#define EXP2(x) __builtin_amdgcn_exp2f(x)
#else
#define EXP2(x) exp2f(x)
#endif

// counted vmcnt wait (T4): retire oldest stage, keep newer stages in flight
#define WAITV(n) asm volatile("s_waitcnt vmcnt(" #n ")" ::: "memory")

// single f32 -> bf16 (RNE) via v_cvt_pk_bf16_f32, 1 VALU inst
__device__ __forceinline__ us f2bf(float f) {
    unsigned r;
    asm("v_cvt_pk_bf16_f32 %0, %1, 0" : "=v"(r) : "v"(f));
    return (us)r;
}
// pack two f32 -> 2x bf16 (lo=a, hi=b), 1 VALU inst
__device__ __forceinline__ unsigned pk2(float a, float b) {
    unsigned r;
    asm("v_cvt_pk_bf16_f32 %0, %1, %2" : "=v"(r) : "v"(a), "v"(b));
    return r;
}
__device__ __forceinline__ float wave_sum(float v) {
#pragma unroll
    for (int o = 32; o > 0; o >>= 1) v += __shfl_xor(v, o);
    return v;
}

// ---------------- weight converts + embed/LN in ONE launch ------------------
// blocks [0,2060): weight cvt + scaled bias (as before)
// blocks [2060,10252): embed+LN, 4 rows/block (one wave per row)
__global__ __launch_bounds__(256) void cvtemb_kernel(
    const float* __restrict__ qw, const float* __restrict__ ow,
    const float* __restrict__ f1, const float* __restrict__ f2,
    const float* __restrict__ qb,
    us* __restrict__ wq, us* __restrict__ wo, us* __restrict__ w1,
    us* __restrict__ w2, float* __restrict__ sb,
    const float* __restrict__ lat, const int* __restrict__ mids,
    const float* __restrict__ pos, const float* __restrict__ ef,
    const float* __restrict__ et,  const float* __restrict__ ep,
    const float* __restrict__ nw,  const float* __restrict__ nb,
    float* __restrict__ x, us* __restrict__ xn)
{
    int blk = blockIdx.x, tid = threadIdx.x;
    if (blk < 2048) {
        const float* s; us* d; int i; float sc = 1.0f;
        if (blk < 768)       { i = blk*256 + tid;        s = qw; d = wq;
                               sc = (((i >> 6) % 768) < 256) ? QSC : 1.0f; }
        else if (blk < 1024) { i = (blk-768)*256 + tid;  s = ow; d = wo; }
        else if (blk < 1536) { i = (blk-1024)*256 + tid; s = f1; d = w1; }
        else                 { i = (blk-1536)*256 + tid; s = f2; d = w2; }
        float4 v = ((const float4*)s)[i];
        uint2 o;
        o.x = pk2(v.x*sc, v.y*sc);
        o.y = pk2(v.z*sc, v.w*sc);
        ((uint2*)d)[i] = o;
    } else if (blk < 2060) {
        int i = (blk-2048)*256 + tid;
        sb[i] = qb[i] * (((i % 768) < 256) ? QSC : 1.0f);
    } else {
        int wv = tid >> 6, lane = tid & 63;
        size_t row = (size_t)(blk - 2060) * 4 + wv;
        int t  = (int)(row & (Tv - 1));
        int id = mids[row];
        int promo = id >> 12;
        int rem   = id & 4095;
        int frm   = rem >> 6;
        int to    = rem & 63;
        float4 v  = ((const float4*)(lat + row*Dv))[lane];
        float4 pv = ((const float4*)(pos + (size_t)t*Dv))[lane];
        float4 fv = ((const float4*)(ef + (size_t)frm*Dv))[lane];
        float4 tv = ((const float4*)(et + (size_t)to*Dv))[lane];
        float4 ev = ((const float4*)(ep + (size_t)promo*Dv))[lane];
        v.x += pv.x + fv.x + tv.x + ev.x;
        v.y += pv.y + fv.y + tv.y + ev.y;
        v.z += pv.z + fv.z + tv.z + ev.z;
        v.w += pv.w + fv.w + tv.w + ev.w;
        ((float4*)(x + row*Dv))[lane] = v;
        float mu = wave_sum(v.x + v.y + v.z + v.w) * (1.0f/Dv);
        float dx = v.x-mu, dy = v.y-mu, dz = v.z-mu, dw = v.w-mu;
        float var = wave_sum(dx*dx + dy*dy + dz*dz + dw*dw) * (1.0f/Dv);
        float inv = rsqrtf(var + EPSv);
        float4 w4 = ((const float4*)nw)[lane];
        float4 b4 = ((const float4*)nb)[lane];
        uint2 o;
        o.x = pk2(dx*inv*w4.x + b4.x, dy*inv*w4.y + b4.y);
        o.y = pk2(dz*inv*w4.z + b4.z, dw*inv*w4.w + b4.w);
        ((uint2*)(xn + row*Dv))[lane] = o;
    }
}

// ---------------- bf16 MFMA GEMM (128x128 tile, BK=64, XOR-swizzled LDS) ----
// T4 counted-vmcnt 2-deep pipeline (r7). Direct scatter-store epilogue.
template<int RELU>
__global__ __launch_bounds__(256) void mm_kernel(
    const us* __restrict__ A, const us* __restrict__ B,
    const float* __restrict__ bias, us* __restrict__ C,
    int M, int N, int K)
{
    __shared__ us As[2][128*64];
    __shared__ us Bs[2][128*64];
    int tid  = threadIdx.x;
    int lane = tid & 63;
    int wu   = __builtin_amdgcn_readfirstlane(tid >> 6);
    int m0 = blockIdx.x * 128, n0 = blockIdx.y * 128;
    int wm = wu & 1, wn = wu >> 1;
    f32x4 acc[4][4] = {};
    int srow = lane >> 3;
    int sg   = (lane & 7) ^ srow;
    const us* Ag = A + (size_t)m0 * K + sg*8;
    const us* Bg = B + (size_t)n0 * K + sg*8;
    int cc = lane & 15, q4 = lane >> 4;

#define STG(kk, bb) { \
    _Pragma("unroll") \
    for (int p = 0; p < 4; p++) { \
        int row = wu*32 + p*8; \
        __builtin_amdgcn_global_load_lds( \
            (const __attribute__((address_space(1))) unsigned int*)(Ag + (size_t)(row + srow)*K + (kk)), \
            (__attribute__((address_space(3))) unsigned int*)(&As[bb][row*64]), \
            16, 0, 0); \
        __builtin_amdgcn_global_load_lds( \
            (const __attribute__((address_space(1))) unsigned int*)(Bg + (size_t)(row + srow)*K + (kk)), \
            (__attribute__((address_space(3))) unsigned int*)(&Bs[bb][row*64]), \
            16, 0, 0); \
    } }

    int nk = K >> 6;
    STG(0, 0);
    if (nk > 1) STG(64, 1);
    int cur = 0;
    for (int t = 0; t < nk; t++) {
        if (t < nk - 1) { WAITV(8); } else { WAITV(0); }   // retire stage t only
        __builtin_amdgcn_s_barrier();
        __builtin_amdgcn_sched_barrier(0);
#pragma unroll
        for (int h = 0; h < 2; h++) {
            int pg = ((h*4 + q4) ^ (cc & 7)) * 8;
            short8 av[4], bv[4];
#pragma unroll
            for (int i = 0; i < 4; i++)
                av[i] = *(const short8*)(&As[cur][(wm*64 + i*16 + cc)*64 + pg]);
#pragma unroll
            for (int j = 0; j < 4; j++)
                bv[j] = *(const short8*)(&Bs[cur][(wn*64 + j*16 + cc)*64 + pg]);
#pragma unroll
            for (int i = 0; i < 4; i++)
#pragma unroll
                for (int j = 0; j < 4; j++)
                    acc[i][j] = __builtin_amdgcn_mfma_f32_16x16x32_bf16(av[i], bv[j], acc[i][j], 0, 0, 0);
        }
        __builtin_amdgcn_sched_barrier(0);
        __builtin_amdgcn_s_barrier();
        __builtin_amdgcn_sched_barrier(0);
        if (t + 2 < nk) STG((t+2)*64, cur);                 // refill freed buffer
        cur ^= 1;
    }
#undef STG
#pragma unroll
    for (int j = 0; j < 4; j++) {
        int n = n0 + wn*64 + j*16 + cc;
        float bj = bias[n];
#pragma unroll
        for (int i = 0; i < 4; i++) {
#pragma unroll
            for (int r = 0; r < 4; r++) {
                int m = m0 + wm*64 + i*16 + q4*4 + r;
                float v = acc[i][j][r] + bj;
                if (RELU) v = fmaxf(v, 0.f);
                C[(size_t)m * N + n] = f2bf(v);
            }
        }
    }
}

// ---------------- fused GEMM 128x256 tile + residual + fused LN -------------
// T4 counted-vmcnt pipeline; residual tile register-prefetched (r10).
// LAST=0: x += gemm ; xn = LN(x)        (mid-network)
// LAST=1: v = x + gemm ; out = mask ? finalLN(v) : latents  — fuses the
//         final_kernel and skips the dead x/xn writes of layer 3's FFN2.
template<int LAST>
__global__ __launch_bounds__(512, 2) void mmfuse_kernel(
    const us* __restrict__ A, const us* __restrict__ B,
    const float* __restrict__ bias, float* __restrict__ x,
    us* __restrict__ xn, const float* __restrict__ nw,
    const float* __restrict__ nb,
    const float* __restrict__ lat, const int* __restrict__ mask,
    float* __restrict__ out, int M, int K)
{
    __shared__ us As[2][128*64];
    __shared__ us Bs[2][256*64];
    __shared__ float red[128][4][2];
    __shared__ float mus[128], rss[128];
    int tid  = threadIdx.x;
    int lane = tid & 63;
    int wu   = __builtin_amdgcn_readfirstlane(tid >> 6);   // 0..7
    int m0 = blockIdx.x * 128;
    int wm = wu & 1, wn = wu >> 1;                          // 2m x 4n waves
    f32x4 acc[4][4] = {};
    int srow = lane >> 3;
    int sg   = (lane & 7) ^ srow;
    const us* Ag = A + (size_t)m0 * K + sg*8;
    const us* Bg = B + sg*8;
    int cc = lane & 15, q4 = lane >> 4;

    // ---- prefetch: residual x tile + bias/LN params -> regs (issued FIRST,
    // oldest in vmcnt queue; done long before the epilogue needs them) ------
    float xr[4][4][4];
    float bb4[4], nwv[4], nbv[4];
#pragma unroll
    for (int i = 0; i < 4; i++)
#pragma unroll
        for (int j = 0; j < 4; j++)
#pragma unroll
            for (int r = 0; r < 4; r++) {
                int ml = wm*64 + i*16 + q4*4 + r;
                xr[i][j][r] = x[(size_t)(m0 + ml) * Dv + wn*64 + j*16 + cc];
            }
#pragma unroll
    for (int j = 0; j < 4; j++) {
        int n = wn*64 + j*16 + cc;
        bb4[j] = bias[n]; nwv[j] = nw[n]; nbv[j] = nb[n];
    }
    __builtin_amdgcn_sched_barrier(0);   // pin prefetch issue before K-loop

#define STG(kk, bb) { \
    _Pragma("unroll") \
    for (int p = 0; p < 2; p++) { \
        int row = wu*16 + p*8; \
        __builtin_amdgcn_global_load_lds( \
            (const __attribute__((address_space(1))) unsigned int*)(Ag + (size_t)(row + srow)*K + (kk)), \
            (__attribute__((address_space(3))) unsigned int*)(&As[bb][row*64]), \
            16, 0, 0); \
    } \
    _Pragma("unroll") \
    for (int p = 0; p < 4; p++) { \
        int row = wu*32 + p*8; \
        __builtin_amdgcn_global_load_lds( \
            (const __attribute__((address_space(1))) unsigned int*)(Bg + (size_t)(row + srow)*K + (kk)), \
            (__attribute__((address_space(3))) unsigned int*)(&Bs[bb][row*64]), \
            16, 0, 0); \
    } }

    int nk = K >> 6;
    STG(0, 0);
    if (nk > 1) STG(64, 1);
    int cur = 0;
    for (int t = 0; t < nk; t++) {
        if (t < nk - 1) { WAITV(6); } else { WAITV(0); }
        __builtin_amdgcn_s_barrier();
        __builtin_amdgcn_sched_barrier(0);
#pragma unroll
        for (int h = 0; h < 2; h++) {
            int pg = ((h*4 + q4) ^ (cc & 7)) * 8;
            short8 av[4], bv[4];
#pragma unroll
            for (int i = 0; i < 4; i++)
                av[i] = *(const short8*)(&As[cur][(wm*64 + i*16 + cc)*64 + pg]);
#pragma unroll
            for (int j = 0; j < 4; j++)
                bv[j] = *(const short8*)(&Bs[cur][(wn*64 + j*16 + cc)*64 + pg]);
#pragma unroll
            for (int i = 0; i < 4; i++)
#pragma unroll
                for (int j = 0; j < 4; j++)
                    acc[i][j] = __builtin_amdgcn_mfma_f32_16x16x32_bf16(av[i], bv[j], acc[i][j], 0, 0, 0);
        }
        __builtin_amdgcn_sched_barrier(0);
        __builtin_amdgcn_s_barrier();
        __builtin_amdgcn_sched_barrier(0);
        if (t + 2 < nk) STG((t+2)*64, cur);
        cur ^= 1;
    }
#undef STG

    // ---- epilogue: bias + residual (regs) + [x write] + row stats ---------
#pragma unroll
    for (int i = 0; i < 4; i++) {
        float s[4] = {0.f,0.f,0.f,0.f}, sq[4] = {0.f,0.f,0.f,0.f};
#pragma unroll
        for (int j = 0; j < 4; j++) {
#pragma unroll
            for (int r = 0; r < 4; r++) {
                int ml = wm*64 + i*16 + q4*4 + r;
                size_t off = (size_t)(m0 + ml) * Dv + wn*64 + j*16 + cc;
                float v = acc[i][j][r] + bb4[j] + xr[i][j][r];
                acc[i][j][r] = v;
                if (!LAST) x[off] = v;
                s[r] += v; sq[r] += v*v;
            }
        }
#pragma unroll
        for (int r = 0; r < 4; r++) {
#pragma unroll
            for (int o = 1; o < 16; o <<= 1) {
                s[r]  += __shfl_xor(s[r],  o);
                sq[r] += __shfl_xor(sq[r], o);
            }
        }
        if (cc == 0) {
#pragma unroll
            for (int r = 0; r < 4; r++) {
                red[wm*64 + i*16 + q4*4 + r][wn][0] = s[r];
                red[wm*64 + i*16 + q4*4 + r][wn][1] = sq[r];
            }
        }
    }
    __syncthreads();
    if (tid < 128) {
        float ts = red[tid][0][0] + red[tid][1][0] + red[tid][2][0] + red[tid][3][0];
        float tq = red[tid][0][1] + red[tid][1][1] + red[tid][2][1] + red[tid][3][1];
        float mu = ts * (1.0f/Dv);
        float var = tq * (1.0f/Dv) - mu*mu;
        mus[tid] = mu;
        rss[tid] = rsqrtf(var + EPSv);
    }
    __syncthreads();
#pragma unroll
    for (int i = 0; i < 4; i++) {
#pragma unroll
        for (int r = 0; r < 4; r++) {
            int ml = wm*64 + i*16 + q4*4 + r;
            float mu = mus[ml], rv = rss[ml];
            if (LAST) {
                int mk = mask[m0 + ml];
                if (mk) {
#pragma unroll
                    for (int j = 0; j < 4; j++) {
                        size_t off = (size_t)(m0 + ml) * Dv + wn*64 + j*16 + cc;
                        out[off] = (acc[i][j][r] - mu)*rv*nwv[j] + nbv[j];
                    }
                } else {
#pragma unroll
                    for (int j = 0; j < 4; j++) {
                        size_t off = (size_t)(m0 + ml) * Dv + wn*64 + j*16 + cc;
                        out[off] = lat[off];
                    }
                }
            } else {
#pragma unroll
                for (int j = 0; j < 4; j++) {
                    size_t off = (size_t)(m0 + ml) * Dv + wn*64 + j*16 + cc;
                    xn[off] = f2bf((acc[i][j][r] - mu)*rv*nwv[j] + nbv[j]);
                }
            }
        }
    }
}

// ---------------- MFMA flash attention (S^T form, 2-deep pipelined) ---------
// Q pre-scaled by 1/sqrt(32)*log2e -> softmax numerator = exp2(s).
// Diag-tile skip: wave wu only needs key sub-tiles jt <= wu (block-causal);
// jt > wu are fully masked -> skip QK MFMA + exp, zero-fill Ps; lane mask
// applied only at jt == wu; PV kk=1 skipped when its P rows are all zero.
__global__ __launch_bounds__(256) void attn_kernel(
    const us* __restrict__ qkv, us* __restrict__ ao)
{
    int blk = blockIdx.x;
    int b  = blk & 63;
    int h  = (blk >> 6) & 7;
    int qt = blk >> 9;
    int i0 = qt << 6;
    int tid = threadIdx.x;
    int lane = tid & 63;
    int wu = tid >> 6;

    __shared__ us Ks[2][64][40];
    __shared__ us Vt[2][32][72];
    __shared__ us Ps[4][16][72];
    __shared__ float Ls[4][16];

    size_t rowbase = (size_t)b * Tv;
    int c = lane & 15, q4 = lane >> 4;

    short8 qfrag = *(const short8*)(qkv + (rowbase + i0 + wu*16 + c)*768 + h*32 + q4*8);

    int skey = tid >> 2, sdc = (tid & 3) << 3;
    int vkey = tid & 63, vg = tid >> 6;
    const us* kgp = qkv + (rowbase + skey)*768 + 256 + h*32 + sdc;
    const us* vgp = qkv + (rowbase + vkey)*768 + 512 + h*32 + vg*8;

    f32x4 oacc[2] = {};
    float lsum = 0.f;
    int ntiles = qt + 1;

    short8 kreg = *(const short8*)(kgp);
    short8 vreg = *(const short8*)(vgp);
    *(short8*)&Ks[0][skey][sdc] = kreg;
#pragma unroll
    for (int j = 0; j < 8; j++) Vt[0][vg*8 + j][vkey] = vreg[j];
    if (ntiles > 1) {
        kreg = *(const short8*)(kgp + 64*768);
        vreg = *(const short8*)(vgp + 64*768);
    }
    __syncthreads();

    for (int kt = 0; kt < ntiles; kt++) {
        int cur = kt & 1;
        if (kt + 1 < ntiles) {
            *(short8*)&Ks[cur^1][skey][sdc] = kreg;
#pragma unroll
            for (int j = 0; j < 8; j++) Vt[cur^1][vg*8 + j][vkey] = vreg[j];
        }
        if (kt + 2 < ntiles) {
            kreg = *(const short8*)(kgp + (size_t)(kt+2)*64*768);
            vreg = *(const short8*)(vgp + (size_t)(kt+2)*64*768);
        }

        bool diag = (kt == ntiles - 1);
        int jtend = diag ? (wu + 1) : 4;      // wave-uniform
        f32x4 st[4];
#pragma unroll
        for (int jt = 0; jt < 4; jt++) {
            if (jt < jtend) {
                short8 kf = *(const short8*)&Ks[cur][jt*16 + c][q4*8];
                st[jt] = __builtin_amdgcn_mfma_f32_16x16x32_bf16(kf, qfrag, (f32x4){0.f,0.f,0.f,0.f}, 0, 0, 0);
            }
        }
#pragma unroll
        for (int jt = 0; jt < 4; jt++) {
            if (jt < jtend) {
                float msk = (diag && jt == wu) ? (((q4 >> 1) <= (c >> 3)) ? 1.f : 0.f) : 1.f;
                float p0 = EXP2(st[jt][0]) * msk;
                float p1 = EXP2(st[jt][1]) * msk;
                float p2 = EXP2(st[jt][2]) * msk;
                float p3 = EXP2(st[jt][3]) * msk;
                lsum += p0 + p1 + p2 + p3;
                uint2 w2; w2.x = pk2(p0, p1); w2.y = pk2(p2, p3);
                *(uint2*)&Ps[wu][c][jt*16 + q4*4] = w2;
            } else {
                uint2 z; z.x = 0u; z.y = 0u;
                *(uint2*)&Ps[wu][c][jt*16 + q4*4] = z;
            }
        }
        int kkend = (diag && wu < 2) ? 1 : 2; // P rows for kk=1 all zero
#pragma unroll
        for (int kk = 0; kk < 2; kk++) {
            if (kk < kkend) {
                short8 pf = *(const short8*)&Ps[wu][c][kk*32 + q4*8];
#pragma unroll
                for (int dt = 0; dt < 2; dt++) {
                    short8 vf = *(const short8*)&Vt[cur][dt*16 + c][kk*32 + q4*8];
                    oacc[dt] = __builtin_amdgcn_mfma_f32_16x16x32_bf16(pf, vf, oacc[dt], 0, 0, 0);
                }
            }
        }
        __syncthreads();
    }

    float l = lsum;
    l += __shfl_xor(l, 16);
    l += __shfl_xor(l, 32);
    if (q4 == 0) Ls[wu][c] = 1.0f / l;
    float4 lv4 = *(const float4*)&Ls[wu][q4*4];
#pragma unroll
    for (int dt = 0; dt < 2; dt++) {
#pragma unroll
        for (int r = 0; r < 4; r++) {
            float li = (r == 0) ? lv4.x : (r == 1) ? lv4.y : (r == 2) ? lv4.z : lv4.w;
            ao[(rowbase + i0 + wu*16 + q4*4 + r)*256 + h*32 + dt*16 + c] = f2bf(oacc[dt][r] * li);
        }
    }
}

// ---------------- launch ----------------------------------------------------
extern "C" void kernel_launch(void* const* d_in, const int* in_sizes, int n_in,
                              void* d_out, int out_size, void* d_ws, size_t ws_size,
                              hipStream_t stream)
{
    const float* latents    = (const float*)d_in[0];
    const int*   move_ids   = (const int*)  d_in[1];
    const int*   mask       = (const int*)  d_in[2];
    const float* positional = (const float*)d_in[3];
    const float* embed_from = (const float*)d_in[4];
    const float* embed_to   = (const float*)d_in[5];
    const float* embed_promo= (const float*)d_in[6];
    const float* in_proj_w  = (const float*)d_in[7];
    const float* in_proj_b  = (const float*)d_in[8];
    const float* out_w      = (const float*)d_in[9];
    const float* out_b      = (const float*)d_in[10];
    const float* fc1_w      = (const float*)d_in[11];
    const float* fc1_b      = (const float*)d_in[12];
    const float* fc2_w      = (const float*)d_in[13];
    const float* fc2_b      = (const float*)d_in[14];
    const float* norm_w     = (const float*)d_in[15];
    const float* norm_b     = (const float*)d_in[16];
    float* out = (float*)d_out;

    float* x   = (float*)d_ws;                              // BT*256 f32
    float* sb  = x + (size_t)BTv * Dv;                      // L*768 f32
    us* xn  = (us*)(sb + Lv*768);                           // BT*256 bf16
    us* qkv = xn + (size_t)BTv * Dv;                        // BT*768
    us* ao  = qkv + (size_t)BTv * 768;                      // BT*256
    us* h1  = ao + (size_t)BTv * Dv;                        // BT*512 bf16 (ffn intermediate)
    us* wq  = h1 + (size_t)BTv * FFv;                       // L*768*256
    us* wo  = wq + (size_t)Lv * 768 * Dv;
    us* w1  = wo + (size_t)Lv * Dv * Dv;
    us* w2  = w1 + (size_t)Lv * FFv * Dv;

    // weight cvt + embed/LN in one dispatch (independent block ranges)
    cvtemb_kernel<<<2060 + BTv/4, 256, 0, stream>>>(
        in_proj_w, out_w, fc1_w, fc2_w, in_proj_b, wq, wo, w1, w2, sb,
        latents, move_ids, positional, embed_from, embed_to, embed_promo,
        norm_w, norm_b, x, xn);

    for (int l = 0; l < Lv; l++) {
        // QKV: 128^2 tile, counted-vmcnt pipeline
        mm_kernel<0><<<dim3(BTv/128, 768/128), 256, 0, stream>>>(
            xn, wq + (size_t)l*768*Dv, sb + l*768, qkv, BTv, 768, Dv);
        attn_kernel<<<Bv*8*(Tv/64), 256, 0, stream>>>(qkv, ao);
        // attn-out proj + residual + LN (K=256)
        mmfuse_kernel<0><<<BTv/128, 512, 0, stream>>>(
            ao, wo + (size_t)l*Dv*Dv, out_b + l*Dv, x, xn, norm_w, norm_b,
            nullptr, nullptr, nullptr, BTv, Dv);
        // FFN phase 1: h1 = relu(xn @ W1^T + b1)
        mm_kernel<1><<<dim3(BTv/128, FFv/128), 256, 0, stream>>>(
            xn, w1 + (size_t)l*FFv*Dv, fc1_b + l*FFv, h1, BTv, FFv, Dv);
        // FFN phase 2 (K=512): mid layers -> x/xn; LAST layer -> fused final
        // LN + mask-select straight to out (skips dead x/xn writes + final_kernel)
        if (l < Lv - 1) {
            mmfuse_kernel<0><<<BTv/128, 512, 0, stream>>>(
                h1, w2 + (size_t)l*Dv*FFv, fc2_b + l*Dv, x, xn, norm_w, norm_b,
                nullptr, nullptr, nullptr, BTv, FFv);
        } else {
            mmfuse_kernel<1><<<BTv/128, 512, 0, stream>>>(
                h1, w2 + (size_t)l*Dv*FFv, fc2_b + l*Dv, x, xn, norm_w, norm_b,
                latents, mask, out, BTv, FFv);
        }
    }
}